// Round 12
// baseline (1225.842 us; speedup 1.0000x reference)
//
#include <hip/hip_runtime.h>

#define S 16384
#define PI_F 3.14159265358979f

struct Ptrs { const float* p[43]; };

// ---- workspace layout (float offsets) ----
enum : int {
  O_SBDC=0, O_SB1=256, O_SB2=512, O_SB3=768, O_SB4=1024, O_SB5=1280,
  O_SBWA=1536, O_SBF=1792, O_SBOA=2048,
  O_M=2304, O_C5=2816, O_NRM=3072, O_GRAM=3328, O_ATT2=7424, O_BEFF=11520,
  O_WB=16384,        // packed hi/lo bf16 weights for dil/oa convs
  O_PART=147456,     // gram/norm partials [256][80]
  O_H=180224,        // gate hidden H[4][4][S] (1 MB)
  O_WP=442368,       // packed hi/lo bf16 1x1 weights (w1|po|wf, 128 KB)
  O_A=524288,        // bf16 P0|P1 conv_dc partials; later AB bf16 overlays P0
  O_FIN=8912896,     // [4][256][S]  c1 | F2 | F3 | F4  (bf16)
  O_CC=25690112,     // [4][64][S]   c2/c3/c4 (bf16), later fused (bf16); dc weights early
  O_DRE=29884416, O_DIMG=34078720,   // f (complex, bf16 SoA); XT lives here pre-FFT
  O_ERE=38273024, O_EIM=42467328,    // scratch; dil/oa XP lives here transiently
  O_G=46661632       // [4][64][S]   later t (oa out, 32ch, bf16)
};
#define APSTRIDE 8388608L   // ushort elements per partial buffer [4][128][S]

typedef short bfrag __attribute__((ext_vector_type(8)));   // 8 bf16 = 4 VGPR
typedef float ffrag __attribute__((ext_vector_type(4)));   // 4 fp32 acc

__device__ __forceinline__ float bf2f(unsigned short u){
  union { unsigned int i; float f; } v; v.i = ((unsigned int)u) << 16; return v.f;
}
__device__ __forceinline__ unsigned short f2bf(float f){
  unsigned int x = __float_as_uint(f);
  unsigned int r = x + 0x7fffu + ((x >> 16) & 1u);
  return (unsigned short)(r >> 16);
}

// ---------------- merged param prep (prep_sb | wt | wtg | wtp) ----------------
// grid 225: [0,9) prep_sb, [9,137) wt, [137,201) wtg, [201,225) wtp
__global__ void prep_all_kernel(Ptrs P, float* ws,
    unsigned short* __restrict__ WHd, unsigned short* __restrict__ WLd,
    unsigned short* __restrict__ WB, unsigned short* __restrict__ WP){
  int bid = blockIdx.x;
  int tid = threadIdx.x;
  if (bid < 9){
    const float r = rsqrtf(1.0f + 1e-5f);
    int bi=0, si=0, oi=0, C=0, dst=0;
    switch (bid){
      case 0: bi=2; si=3; oi=4; C=128; dst=O_SBDC; break;
      case 1: bi=6; si=7; oi=8; C=64; dst=O_SB1; break;
      case 2: bi=10; si=11; oi=12; C=64; dst=O_SB2; break;
      case 3: bi=14; si=15; oi=16; C=64; dst=O_SB3; break;
      case 4: bi=18; si=19; oi=20; C=64; dst=O_SB4; break;
      case 5: bi=22; si=23; oi=24; C=64; dst=O_SB5; break;
      case 6: bi=28; si=29; oi=30; C=4;  dst=O_SBWA; break;
      case 7: bi=34; si=35; oi=36; C=64; dst=O_SBF; break;
      default: bi=38; si=39; oi=40; C=32; dst=O_SBOA; break;
    }
    for (int c = tid; c < C; c += 256){
      float bb = P.p[bi][c], ss = P.p[si][c], oo = P.p[oi][c];
      float sc = ss * r;
      ws[dst + c] = sc;
      ws[dst + C + c] = bb * sc + oo;
    }
    return;
  }
  if (bid < 137){
    const float* w = P.p[1];
    for (int e = (bid - 9)*256 + tid; e < 294912; e += 128*256){
      int c32 = e & 31, co = (e >> 5) & 127, kc = (e >> 12) & 7, sh = e >> 15;
      int ky = sh / 3, kx = sh - ky*3;
      int ci = kc*32 + c32;
      float v = w[((long)(co*256 + ci)*3 + ky)*3 + kx];
      unsigned short h = f2bf(v);
      WHd[e] = h;
      WLd[e] = f2bf(v - bf2f(h));
    }
    return;
  }
  if (bid < 201){
    int lb = bid - 137;
    int gx = lb & 15, gy = lb >> 4;
    const float* w; int cout; long off;
    switch (gy){
      case 0: w = P.p[9];  cout = 64; off = 0;      break;
      case 1: w = P.p[13]; cout = 64; off = 73728;  break;
      case 2: w = P.p[17]; cout = 64; off = 147456; break;
      default: w = P.p[37]; cout = 32; off = 221184; break;
    }
    int total = 576*cout;
    unsigned short* WH = WB + off;
    unsigned short* WL = WH + total;
    for (int e = gx*256 + tid; e < total; e += 16*256){
      int c32 = e & 31;
      int co = (e >> 5) & (cout - 1);
      int kc = (e / (32*cout)) & 1;
      int sh = e / (64*cout);
      int ky = sh/3, kx = sh - ky*3;
      int ci = kc*32 + c32;
      float v = w[((long)(co*64 + ci)*3 + ky)*3 + kx];
      unsigned short h = f2bf(v);
      WH[e] = h;
      WL[e] = f2bf(v - bf2f(h));
    }
    return;
  }
  {
    int lb = bid - 201;
    int gx = lb & 7, gy = lb >> 3;
    const float* w; int KC, wstr; long off;
    switch (gy){
      case 0: w = P.p[5];  KC = 4; wstr = 128; off = 0;     break;
      case 1: w = P.p[26]; KC = 4; wstr = 128; off = 16384; break;
      default: w = P.p[33]; KC = 8; wstr = 320; off = 32768; break;
    }
    int total = KC*64*32;
    unsigned short* WH = WP + off;
    unsigned short* WL = WH + total;
    for (int e = gx*256 + tid; e < total; e += 8*256){
      int c32 = e & 31, co = (e >> 5) & 63, kc = e >> 11;
      float v = w[(long)co*wstr + kc*32 + c32];
      unsigned short h = f2bf(v);
      WH[e] = h;
      WL[e] = f2bf(v - bf2f(h));
    }
  }
}

// ---------------- conv_dc input prepack ----------------
__global__ __launch_bounds__(256) void xpad_kernel(const float* __restrict__ x,
    unsigned short* __restrict__ XT){
  int yy = blockIdx.x, b = blockIdx.y;
  long obase = ((long)(b*130) + yy) * (130L*256);
  int tid = threadIdx.x;
  if (yy == 0 || yy == 129){
    uint4 z; z.x=0; z.y=0; z.z=0; z.w=0;
    for (int i = tid; i < 130*256/8; i += 256)
      *(uint4*)(XT + obase + (long)i*8) = z;
    return;
  }
  __shared__ float LT[64][129];
  int y = yy - 1;
  for (int c0 = 0; c0 < 256; c0 += 64){
    for (int idx = tid; idx < 64*128; idx += 256){
      int ci = idx >> 7, xx = idx & 127;
      LT[ci][xx] = x[((long)(b*256 + c0 + ci)*128 + y)*128 + xx];
    }
    __syncthreads();
    for (int idx = tid; idx < 128*16; idx += 256){
      int xp = idx >> 4, c4 = (idx & 15)*4;
      ushort4 v;
      v.x = f2bf(LT[c4][xp]);   v.y = f2bf(LT[c4+1][xp]);
      v.z = f2bf(LT[c4+2][xp]); v.w = f2bf(LT[c4+3][xp]);
      *(ushort4*)(XT + obase + (long)(xp+1)*256 + c0 + c4) = v;
    }
    __syncthreads();
  }
  if (tid < 64){
    ushort4 z; z.x=0; z.y=0; z.z=0; z.w=0;
    *(ushort4*)(XT + obase + tid*4) = z;
    *(ushort4*)(XT + obase + 129L*256 + tid*4) = z;
  }
}

// pad+pack 64ch input; BF16IN=1: in1/in2 bf16 planes (sum), else fp32 (in2 unused)
template<int DIL, int BF16IN>
__global__ __launch_bounds__(256) void xpad64_kernel(const void* __restrict__ in1,
    const void* __restrict__ in2, long in_bs, unsigned short* __restrict__ XP){
  constexpr int TW = 128 + 2*DIL;
  int yy = blockIdx.x, b = blockIdx.y;
  long obase = (long)(b*TW + yy) * TW * 64;
  int tid = threadIdx.x;
  if (yy < DIL || yy >= 128 + DIL){
    uint4 z; z.x=0; z.y=0; z.z=0; z.w=0;
    for (int i = tid; i < TW*8; i += 256)
      *(uint4*)(XP + obase + (long)i*8) = z;
    return;
  }
  __shared__ float LT[64][129];
  int y = yy - DIL;
  if (BF16IN){
    const unsigned short* p1 = (const unsigned short*)in1 + (long)b*in_bs + (long)y*128;
    const unsigned short* p2 = in2 ? (const unsigned short*)in2 + (long)b*in_bs + (long)y*128 : nullptr;
    for (int idx = tid; idx < 64*64; idx += 256){
      int ci = idx >> 6, x2 = (idx & 63)*2;
      ushort2 u1 = *(const ushort2*)(p1 + (long)ci*S + x2);
      float a0 = bf2f(u1.x), a1 = bf2f(u1.y);
      if (p2){
        ushort2 u2 = *(const ushort2*)(p2 + (long)ci*S + x2);
        a0 += bf2f(u2.x); a1 += bf2f(u2.y);
      }
      LT[ci][x2] = a0; LT[ci][x2+1] = a1;
    }
  } else {
    const float* p1 = (const float*)in1 + (long)b*in_bs + (long)y*128;
    for (int idx = tid; idx < 64*128; idx += 256){
      int ci = idx >> 7, xx = idx & 127;
      LT[ci][xx] = p1[(long)ci*S + xx];
    }
  }
  __syncthreads();
  for (int i = tid; i < 2*DIL*16; i += 256){
    int side = i / (DIL*16);
    int r = i - side*(DIL*16);
    int xcol = side ? (128 + DIL + (r >> 4)) : (r >> 4);
    ushort4 z; z.x=0; z.y=0; z.z=0; z.w=0;
    *(ushort4*)(XP + obase + (long)xcol*64 + (r & 15)*4) = z;
  }
  for (int idx = tid; idx < 128*16; idx += 256){
    int xp = idx >> 4, c4 = (idx & 15)*4;
    ushort4 v;
    v.x = f2bf(LT[c4][xp]);   v.y = f2bf(LT[c4+1][xp]);
    v.z = f2bf(LT[c4+2][xp]); v.w = f2bf(LT[c4+3][xp]);
    *(ushort4*)(XP + obase + (long)(xp + DIL)*64 + c4) = v;
  }
}

// ---------------- conv_dc K-split: raw bf16 partials, 2048 blocks ----------------
// Single bf16 weights (round-9 config: 67us best measured).
__global__ __launch_bounds__(256) void convdc_split_kernel(
    const unsigned short* __restrict__ XP,
    const unsigned short* __restrict__ WH,
    unsigned short* __restrict__ out){
  constexpr int CIN = 256, TW = 130, LDA = 36, NSTG = 3;
  __shared__ unsigned short As[2][TW*LDA];
  int bid = blockIdx.x;
  int y = (bid & 7)*16 + ((bid >> 3) & 15);
  int b = (bid >> 7) & 3;
  int n2 = (bid >> 9) & 1;
  int ks = bid >> 10;
  int tid = threadIdx.x, wv = tid >> 6, lane = tid & 63;
  int mhalf = wv & 1, nhalf = wv >> 1;
  int px0 = mhalf*64;
  ffrag acc[4][2];
  #pragma unroll
  for (int i = 0; i < 4; i++)
    #pragma unroll
    for (int j = 0; j < 2; j++)
      #pragma unroll
      for (int r = 0; r < 4; r++) acc[i][j][r] = 0.f;
  int kq = (lane >> 4)*8, rown = lane & 15;
  int sx = tid >> 2, sq = tid & 3;
  int cobase = n2*64 + nhalf*32;
  {
    long rowbase = ((long)(b*TW + y))*TW*CIN + (ks*4)*32 + sq*8;
    #pragma unroll
    for (int t = 0; t < NSTG; t++){
      int x = sx + 64*t;
      int xc = x < TW ? x : TW - 1;
      uint4 v = *(const uint4*)(XP + rowbase + (long)xc*CIN);
      if (x < TW) *(uint4*)&As[0][x*LDA + sq*8] = v;
    }
  }
  __syncthreads();
  for (int s = 0; s < 12; s++){
    int cur = s & 1;
    int ky = s >> 2, kcl = s & 3;
    int kc = ks*4 + kcl;
    int s2 = (s + 1 < 12) ? s + 1 : s;
    int ky2 = s2 >> 2, kc2 = ks*4 + (s2 & 3);
    uint4 pre[NSTG];
    {
      long rowbase = ((long)(b*TW + y + ky2))*TW*CIN + kc2*32 + sq*8;
      #pragma unroll
      for (int t = 0; t < NSTG; t++){
        int x = sx + 64*t;
        int xc = x < TW ? x : TW - 1;
        pre[t] = *(const uint4*)(XP + rowbase + (long)xc*CIN);
      }
    }
    #pragma unroll
    for (int kx = 0; kx < 3; kx++){
      int step = (ky*3 + kx)*8 + kc;
      bfrag bhf[2];
      #pragma unroll
      for (int j = 0; j < 2; j++){
        long wb = ((long)step*128 + cobase + j*16 + rown)*32 + kq;
        bhf[j] = *(const bfrag*)(WH + wb);
      }
      bfrag af[4];
      #pragma unroll
      for (int i = 0; i < 4; i++){
        int x = px0 + i*16 + rown + kx;
        af[i] = *(const bfrag*)&As[cur][x*LDA + kq];
      }
      #pragma unroll
      for (int i = 0; i < 4; i++)
        #pragma unroll
        for (int j = 0; j < 2; j++)
          acc[i][j] = __builtin_amdgcn_mfma_f32_16x16x32_bf16(af[i], bhf[j], acc[i][j], 0, 0, 0);
    }
    #pragma unroll
    for (int t = 0; t < NSTG; t++){
      int x = sx + 64*t;
      if (x < TW) *(uint4*)&As[cur ^ 1][x*LDA + sq*8] = pre[t];
    }
    __syncthreads();
  }
  unsigned short* dst = out + ks*APSTRIDE;
  #pragma unroll
  for (int i = 0; i < 4; i++){
    int pixel = px0 + i*16 + (lane >> 4)*4;
    #pragma unroll
    for (int j = 0; j < 2; j++){
      int co = cobase + j*16 + (lane & 15);
      ushort4 w;
      w.x = f2bf(acc[i][j][0]); w.y = f2bf(acc[i][j][1]);
      w.z = f2bf(acc[i][j][2]); w.w = f2bf(acc[i][j][3]);
      *(ushort4*)(dst + ((long)(b*128 + co))*S + y*128 + pixel) = w;
    }
  }
}

// ---------------- 3x3 conv via MFMA implicit GEMM ------
// HILO=1: hi/lo dual-MFMA weights; HILO=0: single bf16 weights (half MFMA+traffic).
template<int DIL, int KC, int NBLK, int BF16OUT, int HILO>
__global__ __launch_bounds__(256) void conv3x3_mfma_kernel(
    const unsigned short* __restrict__ XP,
    const unsigned short* __restrict__ WH, const unsigned short* __restrict__ WL,
    const float* __restrict__ scbi, void* __restrict__ out){
  constexpr int CIN = KC*32;
  constexpr int TW = 128 + 2*DIL;
  constexpr int NJ = NBLK/32;
  constexpr int LDA = 36;
  constexpr int NSTG = (TW + 63)/64;
  constexpr int NS = 3*KC;
  __shared__ unsigned short As[2][TW*LDA];
  int bid = blockIdx.x;
  int y = (bid & 7)*16 + ((bid >> 3) & 15);
  int b = (bid >> 7) & 3;
  int n2 = bid >> 9;
  int nb = gridDim.x >> 9; if (nb == 0) nb = 1;
  int coutTotal = nb * NBLK;
  int tid = threadIdx.x, wv = tid >> 6, lane = tid & 63;
  int mhalf = wv & 1, nhalf = wv >> 1;
  int px0 = mhalf*64;
  ffrag acc[4][NJ];
  #pragma unroll
  for (int i = 0; i < 4; i++)
    #pragma unroll
    for (int j = 0; j < NJ; j++)
      #pragma unroll
      for (int r = 0; r < 4; r++) acc[i][j][r] = 0.f;

  int kq = (lane >> 4)*8, rown = lane & 15;
  int sx = tid >> 2, sq = tid & 3;
  int cobase = n2*NBLK + nhalf*(NBLK/2);

  {
    long rowbase = ((long)(b*TW + y))*TW*CIN + sq*8;
    #pragma unroll
    for (int t = 0; t < NSTG; t++){
      int x = sx + 64*t;
      int xc = x < TW ? x : TW - 1;
      uint4 v = *(const uint4*)(XP + rowbase + (long)xc*CIN);
      if (x < TW) *(uint4*)&As[0][x*LDA + sq*8] = v;
    }
  }
  __syncthreads();

  for (int s = 0; s < NS; s++){
    int cur = s & 1;
    int ky = s / KC, kc = s - ky*KC;
    int s2 = (s + 1 < NS) ? s + 1 : s;
    int ky2 = s2 / KC, kc2 = s2 - ky2*KC;
    uint4 pre[NSTG];
    {
      long rowbase = ((long)(b*TW + y + ky2*DIL))*TW*CIN + kc2*32 + sq*8;
      #pragma unroll
      for (int t = 0; t < NSTG; t++){
        int x = sx + 64*t;
        int xc = x < TW ? x : TW - 1;
        pre[t] = *(const uint4*)(XP + rowbase + (long)xc*CIN);
      }
    }
    #pragma unroll
    for (int kx = 0; kx < 3; kx++){
      int step = (ky*3 + kx)*KC + kc;
      bfrag bhf[NJ], blf[NJ];
      #pragma unroll
      for (int j = 0; j < NJ; j++){
        long wb = ((long)step*coutTotal + cobase + j*16 + rown)*32 + kq;
        bhf[j] = *(const bfrag*)(WH + wb);
        if (HILO) blf[j] = *(const bfrag*)(WL + wb);
      }
      bfrag af[4];
      #pragma unroll
      for (int i = 0; i < 4; i++){
        int x = px0 + i*16 + rown + kx*DIL;
        af[i] = *(const bfrag*)&As[cur][x*LDA + kq];
      }
      #pragma unroll
      for (int i = 0; i < 4; i++)
        #pragma unroll
        for (int j = 0; j < NJ; j++){
          if (HILO)
            acc[i][j] = __builtin_amdgcn_mfma_f32_16x16x32_bf16(af[i], blf[j], acc[i][j], 0, 0, 0);
          acc[i][j] = __builtin_amdgcn_mfma_f32_16x16x32_bf16(af[i], bhf[j], acc[i][j], 0, 0, 0);
        }
    }
    #pragma unroll
    for (int t = 0; t < NSTG; t++){
      int x = sx + 64*t;
      if (x < TW) *(uint4*)&As[cur ^ 1][x*LDA + sq*8] = pre[t];
    }
    __syncthreads();
  }
  #pragma unroll
  for (int i = 0; i < 4; i++){
    int pixel = px0 + i*16 + (lane >> 4)*4;
    #pragma unroll
    for (int j = 0; j < NJ; j++){
      int co = cobase + j*16 + (lane & 15);
      float sc = scbi[co], bb = scbi[coutTotal + co];
      long ooff = ((long)(b*coutTotal + co))*S + y*128 + pixel;
      if (BF16OUT){
        ushort4 w;
        w.x = f2bf(fmaxf(acc[i][j][0]*sc + bb, 0.f));
        w.y = f2bf(fmaxf(acc[i][j][1]*sc + bb, 0.f));
        w.z = f2bf(fmaxf(acc[i][j][2]*sc + bb, 0.f));
        w.w = f2bf(fmaxf(acc[i][j][3]*sc + bb, 0.f));
        *(ushort4*)((unsigned short*)out + ooff) = w;
      } else {
        float* op = (float*)out + ooff;
        #pragma unroll
        for (int r = 0; r < 4; r++)
          op[r] = fmaxf(acc[i][j][r]*sc + bb, 0.f);
      }
    }
  }
}

// ---------------- 1x1 conv via MFMA ----
// B (weights) global-direct. A double-buffered in LDS, one barrier per kc.
// MODE 0: bn_relu | 1: +residual | 2: per-(b,co) bias.
// BF16IN: 0 fp32 | 1 bf16 | 2 combine bf16 partials P0/P1 w/ dc bn_relu (beff table).
// HILO=0: single bf16 weights.
template<int MODE, int KC, int BF16IN, int BF16OUT, int HILO>
__global__ __launch_bounds__(256) void conv1x1_mfma_kernel(
    const void* __restrict__ inv, long in_bs,
    const unsigned short* __restrict__ WH, const unsigned short* __restrict__ WL,
    const float* __restrict__ scbi, const float* __restrict__ beff,
    const unsigned short* __restrict__ res, long res_bs,
    void* __restrict__ outv, long out_bs){
  constexpr int LDA = 36;
  __shared__ unsigned short Als[2][128*LDA];
  int bid = blockIdx.x;
  int y = (bid & 7)*16 + ((bid >> 3) & 15);
  int b = bid >> 7;
  int tid = threadIdx.x, wv = tid >> 6, lane = tid & 63;
  int mt0 = (wv & 1)*4, nt0 = (wv >> 1)*2;
  ffrag acc[4][2];
  #pragma unroll
  for (int i = 0; i < 4; i++)
    #pragma unroll
    for (int j = 0; j < 2; j++)
      #pragma unroll
      for (int r = 0; r < 4; r++) acc[i][j][r] = 0.f;
  int pq = tid & 31, cg = tid >> 5;
  int kq = (lane >> 4)*8, rown = lane & 15;
  const float* ibf = (const float*)inv + (long)b*in_bs + y*128;
  const unsigned short* ibs = (const unsigned short*)inv + (long)b*in_bs + y*128;
  unsigned short a[16];
  #pragma unroll
  for (int cc = 0; cc < 4; cc++)
    #pragma unroll
    for (int i = 0; i < 4; i++){
      long off = (long)(cg*4 + cc)*S + pq + 32*i;
      if (BF16IN == 1) a[cc*4 + i] = ibs[off];
      else if (BF16IN == 2){
        float v = bf2f(ibs[off]) + bf2f(ibs[off + APSTRIDE]);
        int ci = cg*4 + cc;
        a[cc*4 + i] = f2bf(fmaxf(v*beff[ci] + beff[128 + ci], 0.f));
      } else a[cc*4 + i] = f2bf(ibf[off]);
    }
  #pragma unroll
  for (int i = 0; i < 4; i++){
    ushort4 v;
    v.x = a[0 + i];  v.y = a[4 + i];
    v.z = a[8 + i];  v.w = a[12 + i];
    *(ushort4*)&Als[0][(pq + 32*i)*LDA + cg*4] = v;
  }
  __syncthreads();
  for (int kc = 0; kc < KC; kc++){
    int cur = kc & 1;
    int kcn = (kc + 1 < KC) ? kc + 1 : kc;
    #pragma unroll
    for (int cc = 0; cc < 4; cc++)
      #pragma unroll
      for (int i = 0; i < 4; i++){
        long off = (long)(kcn*32 + cg*4 + cc)*S + pq + 32*i;
        if (BF16IN == 1) a[cc*4 + i] = ibs[off];
        else if (BF16IN == 2){
          float v = bf2f(ibs[off]) + bf2f(ibs[off + APSTRIDE]);
          int ci = kcn*32 + cg*4 + cc;
          a[cc*4 + i] = f2bf(fmaxf(v*beff[ci] + beff[128 + ci], 0.f));
        } else a[cc*4 + i] = f2bf(ibf[off]);
      }
    bfrag af[4], bhf[2], blf[2];
    #pragma unroll
    for (int j = 0; j < 2; j++){
      long wb = ((long)kc*64 + (nt0 + j)*16 + rown)*32 + kq;
      bhf[j] = *(const bfrag*)(WH + wb);
      if (HILO) blf[j] = *(const bfrag*)(WL + wb);
    }
    #pragma unroll
    for (int i = 0; i < 4; i++)
      af[i] = *(const bfrag*)&Als[cur][((mt0 + i)*16 + rown)*LDA + kq];
    #pragma unroll
    for (int i = 0; i < 4; i++)
      #pragma unroll
      for (int j = 0; j < 2; j++){
        if (HILO)
          acc[i][j] = __builtin_amdgcn_mfma_f32_16x16x32_bf16(af[i], blf[j], acc[i][j], 0, 0, 0);
        acc[i][j] = __builtin_amdgcn_mfma_f32_16x16x32_bf16(af[i], bhf[j], acc[i][j], 0, 0, 0);
      }
    #pragma unroll
    for (int i = 0; i < 4; i++){
      ushort4 v;
      v.x = a[0 + i];  v.y = a[4 + i];
      v.z = a[8 + i];  v.w = a[12 + i];
      *(ushort4*)&Als[cur ^ 1][(pq + 32*i)*LDA + cg*4] = v;
    }
    __syncthreads();
  }
  #pragma unroll
  for (int i = 0; i < 4; i++){
    int pixel = (mt0 + i)*16 + (lane >> 4)*4;
    #pragma unroll
    for (int j = 0; j < 2; j++){
      int co = (nt0 + j)*16 + (lane & 15);
      long ooff = (long)b*out_bs + (long)co*S + y*128 + pixel;
      float vv[4];
      if (MODE == 1){
        ushort4 rv = *(const ushort4*)(res + (long)b*res_bs + (long)co*S + y*128 + pixel);
        vv[0] = acc[i][j][0] + bf2f(rv.x);
        vv[1] = acc[i][j][1] + bf2f(rv.y);
        vv[2] = acc[i][j][2] + bf2f(rv.z);
        vv[3] = acc[i][j][3] + bf2f(rv.w);
      } else if (MODE == 0){
        #pragma unroll
        for (int r = 0; r < 4; r++)
          vv[r] = fmaxf(acc[i][j][r]*scbi[co] + scbi[64 + co], 0.f);
      } else {
        #pragma unroll
        for (int r = 0; r < 4; r++)
          vv[r] = fmaxf(acc[i][j][r]*scbi[co] + beff[b*64 + co], 0.f);
      }
      if (BF16OUT){
        ushort4 w;
        w.x = f2bf(vv[0]); w.y = f2bf(vv[1]); w.z = f2bf(vv[2]); w.w = f2bf(vv[3]);
        *(ushort4*)((unsigned short*)outv + ooff) = w;
      } else {
        float* op = (float*)outv + ooff;
        #pragma unroll
        for (int r = 0; r < 4; r++) op[r] = vv[r];
      }
    }
  }
}

// ---------------- FFT-128 with hoisted lane twiddles ----------------
__device__ __forceinline__ void fft128_mk_tw(float (&tws)[8], float (&twc)[8],
                                             float sign, int lane){
  float a0 = sign * (2.0f*PI_F/128.0f) * (float)lane;
  __sincosf(a0, &tws[0], &twc[0]);
  int i = 1;
  #pragma unroll
  for (int h = 32; h >= 1; h >>= 1, i++){
    int j = lane & (h - 1);
    float a = sign * (2.0f*PI_F/128.0f) * (float)(j * (64/h));
    __sincosf(a, &tws[i], &twc[i]);
  }
}

__device__ __forceinline__ void fft128(float& z0r, float& z0i, float& z1r, float& z1i,
    const float (&tws)[8], const float (&twc)[8], int lane){
  {
    float ar = z0r, ai = z0i, br = z1r, bi = z1i;
    z0r = ar + br; z0i = ai + bi;
    float dr = ar - br, di = ai - bi;
    float s = tws[0], c = twc[0];
    z1r = dr*c - di*s; z1i = dr*s + di*c;
  }
  int idx = 1;
  #pragma unroll
  for (int h = 32; h >= 1; h >>= 1, idx++){
    float s = tws[idx], c = twc[idx];
    bool up = (lane & h) != 0;
    float pr, pi, nr, ni;
    pr = __shfl_xor(z0r, h, 64); pi = __shfl_xor(z0i, h, 64);
    if (!up){ nr = z0r + pr; ni = z0i + pi; }
    else { float dr = pr - z0r, di = pi - z0i; nr = dr*c - di*s; ni = dr*s + di*c; }
    z0r = nr; z0i = ni;
    pr = __shfl_xor(z1r, h, 64); pi = __shfl_xor(z1i, h, 64);
    if (!up){ nr = z1r + pr; ni = z1i + pi; }
    else { float dr = pr - z1r, di = pi - z1i; nr = dr*c - di*s; ni = dr*s + di*c; }
    z1r = nr; z1i = ni;
  }
}

// ---------------- fused per-plane 2D FFT kernels ----------------

// fwd fft2: bf16 plane -> bf16 D[yfreq][xfreq]
__global__ __launch_bounds__(1024) void fft2_fwd_kernel(const unsigned short* __restrict__ in,
    unsigned short* __restrict__ outRe, unsigned short* __restrict__ outIm){
  __shared__ float lre[128][129];
  __shared__ float lim[128][129];
  int plane = blockIdx.x;
  int tid = threadIdx.x, wv = tid >> 6, lane = tid & 63;
  long pbase = (long)plane * S;
  for (int i = tid; i < S/4; i += 1024){
    int px = i*4; int r = px >> 7, c = px & 127;
    ushort4 v = *(const ushort4*)(in + pbase + px);
    lre[r][c] = bf2f(v.x); lre[r][c+1] = bf2f(v.y);
    lre[r][c+2] = bf2f(v.z); lre[r][c+3] = bf2f(v.w);
  }
  float tws[8], twc[8];
  fft128_mk_tw(tws, twc, -1.0f, lane);
  __syncthreads();
  #pragma unroll
  for (int rr = 0; rr < 8; rr++){
    int r = wv*8 + rr;
    float z0r = lre[r][lane], z0i = 0.f;
    float z1r = lre[r][lane + 64], z1i = 0.f;
    fft128(z0r, z0i, z1r, z1i, tws, twc, lane);
    int k = __brev(lane) >> 25;
    lre[r][k] = z0r;     lim[r][k] = z0i;
    lre[r][k+1] = z1r;   lim[r][k+1] = z1i;
  }
  __syncthreads();
  #pragma unroll
  for (int cc = 0; cc < 8; cc++){
    int c = wv*8 + cc;
    float z0r = lre[lane][c], z0i = lim[lane][c];
    float z1r = lre[lane + 64][c], z1i = lim[lane + 64][c];
    fft128(z0r, z0i, z1r, z1i, tws, twc, lane);
    int k = __brev(lane) >> 25;
    lre[k][c] = z0r;     lim[k][c] = z0i;
    lre[k+1][c] = z1r;   lim[k+1][c] = z1i;
  }
  __syncthreads();
  for (int i = tid; i < S/2; i += 1024){
    int px = i*2; int r = px >> 7, c = px & 127;
    ushort2 vr, vi;
    vr.x = f2bf(lre[r][c]); vr.y = f2bf(lre[r][c+1]);
    vi.x = f2bf(lim[r][c]); vi.y = f2bf(lim[r][c+1]);
    *(ushort2*)(outRe + pbase + px) = vr;
    *(ushort2*)(outIm + pbase + px) = vi;
  }
}

// ol: gate-premul + col IFFT + row IFFT + abs -> AB[64..128)
__global__ __launch_bounds__(1024) void ifft2_gate_abs_ol_kernel(
    const unsigned short* __restrict__ Dre, const unsigned short* __restrict__ Dim,
    const float* __restrict__ H, const float* __restrict__ wb, const float* __restrict__ bwb,
    unsigned short* __restrict__ AB){
  __shared__ float lre[128][129];
  __shared__ float lim[128][129];
  int plane = blockIdx.x;             // b*64 + ch
  int b = plane >> 6, ch = plane & 63;
  int tid = threadIdx.x, wv = tid >> 6, lane = tid & 63;
  long pbase = (long)plane * S;
  float w0 = wb[ch*4], w1 = wb[ch*4+1], w2 = wb[ch*4+2], w3 = wb[ch*4+3];
  float bw = bwb[ch];
  const float* Hb = H + (long)b*4*S;
  for (int i = tid; i < S/2; i += 1024){
    int px = i*2;
    float2 h0 = *(const float2*)(Hb + px);
    float2 h1 = *(const float2*)(Hb + S + px);
    float2 h2 = *(const float2*)(Hb + 2*S + px);
    float2 h3 = *(const float2*)(Hb + 3*S + px);
    ushort2 ur = *(const ushort2*)(Dre + pbase + px);
    ushort2 ui = *(const ushort2*)(Dim + pbase + px);
    float hva = bw + w0*h0.x + w1*h1.x + w2*h2.x + w3*h3.x;
    float hvb = bw + w0*h0.y + w1*h1.y + w2*h2.y + w3*h3.y;
    float ga = 1.0f / (1.0f + __expf(-hva));
    float gb = 1.0f / (1.0f + __expf(-hvb));
    int r = px >> 7, c = px & 127;
    lre[r][c]   = bf2f(ur.x) * ga;  lim[r][c]   = bf2f(ui.x) * ga;
    lre[r][c+1] = bf2f(ur.y) * gb;  lim[r][c+1] = bf2f(ui.y) * gb;
  }
  float tws[8], twc[8];
  fft128_mk_tw(tws, twc, 1.0f, lane);
  __syncthreads();
  #pragma unroll
  for (int cc = 0; cc < 8; cc++){
    int c = wv*8 + cc;
    float z0r = lre[lane][c], z0i = lim[lane][c];
    float z1r = lre[lane + 64][c], z1i = lim[lane + 64][c];
    fft128(z0r, z0i, z1r, z1i, tws, twc, lane);
    int k = __brev(lane) >> 25;
    lre[k][c] = z0r;     lim[k][c] = z0i;
    lre[k+1][c] = z1r;   lim[k+1][c] = z1i;
  }
  __syncthreads();
  unsigned short* out = AB + ((long)(b*128 + 64 + ch)) * S;
  #pragma unroll
  for (int rr = 0; rr < 8; rr++){
    int r = wv*8 + rr;
    float z0r = lre[r][lane], z0i = lim[r][lane];
    float z1r = lre[r][lane + 64], z1i = lim[r][lane + 64];
    fft128(z0r, z0i, z1r, z1i, tws, twc, lane);
    int k = __brev(lane) >> 25;
    ushort2 v;
    v.x = f2bf(sqrtf(z0r*z0r + z0i*z0i) * (1.0f/16384.0f));
    v.y = f2bf(sqrtf(z1r*z1r + z1i*z1i) * (1.0f/16384.0f));
    *(ushort2*)(out + (long)r*128 + k) = v;
  }
}

// of: attn channel-mix + col IFFT + 4-step twiddle + row IFFT + abs + transposed store
__global__ __launch_bounds__(1024) void ifft2_attn_abs_ofT_kernel(
    const unsigned short* __restrict__ Dre, const unsigned short* __restrict__ Dim,
    const float* __restrict__ ATT2, unsigned short* __restrict__ AB){
  __shared__ float lre[128][129];
  __shared__ float lim[128][129];
  int plane = blockIdx.x;             // b*64 + (h*8+cp)
  int b = plane >> 6, ch = plane & 63;
  int bh = plane >> 3;
  int cp = plane & 7;
  int tid = threadIdx.x, wv = tid >> 6, lane = tid & 63;
  long hbase = (long)bh * 8 * S;
  float wr[8], wi[8];
  #pragma unroll
  for (int d = 0; d < 8; d++){
    wr[d] = ATT2[bh*128 + (cp*8 + d)*2];
    wi[d] = ATT2[bh*128 + (cp*8 + d)*2 + 1];
  }
  for (int i = tid; i < S/4; i += 1024){
    int px = i*4;
    float sr0=0.f, si0=0.f, sr1=0.f, si1=0.f, sr2=0.f, si2=0.f, sr3=0.f, si3=0.f;
    #pragma unroll
    for (int d = 0; d < 8; d++){
      ushort4 ur = *(const ushort4*)(Dre + hbase + (long)d*S + px);
      ushort4 ui = *(const ushort4*)(Dim + hbase + (long)d*S + px);
      float xr0 = bf2f(ur.x), xi0 = bf2f(ui.x);
      float xr1 = bf2f(ur.y), xi1 = bf2f(ui.y);
      float xr2 = bf2f(ur.z), xi2 = bf2f(ui.z);
      float xr3 = bf2f(ur.w), xi3 = bf2f(ui.w);
      sr0 += wr[d]*xr0 - wi[d]*xi0;  si0 += wr[d]*xi0 + wi[d]*xr0;
      sr1 += wr[d]*xr1 - wi[d]*xi1;  si1 += wr[d]*xi1 + wi[d]*xr1;
      sr2 += wr[d]*xr2 - wi[d]*xi2;  si2 += wr[d]*xi2 + wi[d]*xr2;
      sr3 += wr[d]*xr3 - wi[d]*xi3;  si3 += wr[d]*xi3 + wi[d]*xr3;
    }
    int r = px >> 7, c = px & 127;
    lre[r][c]   = sr0;  lim[r][c]   = si0;
    lre[r][c+1] = sr1;  lim[r][c+1] = si1;
    lre[r][c+2] = sr2;  lim[r][c+2] = si2;
    lre[r][c+3] = sr3;  lim[r][c+3] = si3;
  }
  float tws[8], twc[8];
  fft128_mk_tw(tws, twc, 1.0f, lane);
  __syncthreads();
  #pragma unroll
  for (int cc = 0; cc < 8; cc++){
    int c = wv*8 + cc;
    float z0r = lre[lane][c], z0i = lim[lane][c];
    float z1r = lre[lane + 64][c], z1i = lim[lane + 64][c];
    fft128(z0r, z0i, z1r, z1i, tws, twc, lane);
    int k = __brev(lane) >> 25;
    float s, co;
    float a0 = (2.0f*PI_F/16384.0f) * (float)(c * k);
    __sincosf(a0, &s, &co);
    float t = z0r*co - z0i*s; z0i = z0r*s + z0i*co; z0r = t;
    float a1 = (2.0f*PI_F/16384.0f) * (float)(c * (k + 1));
    __sincosf(a1, &s, &co);
    t = z1r*co - z1i*s; z1i = z1r*s + z1i*co; z1r = t;
    lre[k][c] = z0r;     lim[k][c] = z0i;
    lre[k+1][c] = z1r;   lim[k+1][c] = z1i;
  }
  __syncthreads();
  float absv[8][2];
  #pragma unroll
  for (int rr = 0; rr < 8; rr++){
    int r = wv*8 + rr;
    float z0r = lre[r][lane], z0i = lim[r][lane];
    float z1r = lre[r][lane + 64], z1i = lim[r][lane + 64];
    fft128(z0r, z0i, z1r, z1i, tws, twc, lane);
    absv[rr][0] = sqrtf(z0r*z0r + z0i*z0i) * (1.0f/16384.0f);
    absv[rr][1] = sqrtf(z1r*z1r + z1i*z1i) * (1.0f/16384.0f);
  }
  __syncthreads();
  int k2 = __brev(lane) >> 25;
  #pragma unroll
  for (int rr = 0; rr < 8; rr++){
    int r = wv*8 + rr;
    lre[k2][r] = absv[rr][0];
    lre[k2+1][r] = absv[rr][1];
  }
  __syncthreads();
  unsigned short* out = AB + ((long)(b*128 + ch)) * S;
  for (int i = tid; i < S/2; i += 1024){
    int px = i*2; int r = px >> 7, c = px & 127;
    ushort2 v;
    v.x = f2bf(lre[r][c]); v.y = f2bf(lre[r][c+1]);
    *(ushort2*)(out + px) = v;
  }
}

// ---------------- attention stats (bf16 f) ----------------
__global__ __launch_bounds__(256) void gram_part_kernel(
    const unsigned short* __restrict__ Dre, const unsigned short* __restrict__ Dim,
    float* __restrict__ PART){
  int bh = blockIdx.x, slab = blockIdx.y;
  long base = (long)bh * 8 * S;
  int n0 = slab * 2048;
  float accr[36], acci[36], nsq[8];
  #pragma unroll
  for (int i = 0; i < 36; i++){ accr[i] = 0.f; acci[i] = 0.f; }
  #pragma unroll
  for (int i = 0; i < 8; i++) nsq[i] = 0.f;
  for (int it = 0; it < 4; it++){
    int n = n0 + (it*256 + threadIdx.x)*2;
    float xr[8][2], xi[8][2];
    #pragma unroll
    for (int c = 0; c < 8; c++){
      ushort2 ur = *(const ushort2*)(Dre + base + (long)c*S + n);
      ushort2 ui = *(const ushort2*)(Dim + base + (long)c*S + n);
      xr[c][0] = bf2f(ur.x); xr[c][1] = bf2f(ur.y);
      xi[c][0] = bf2f(ui.x); xi[c][1] = bf2f(ui.y);
      nsq[c] += xr[c][0]*xr[c][0] + xi[c][0]*xi[c][0]
              + xr[c][1]*xr[c][1] + xi[c][1]*xi[c][1];
    }
    int t = 0;
    #pragma unroll
    for (int c = 0; c < 8; c++)
      #pragma unroll
      for (int d = c; d < 8; d++){
        accr[t] += xr[c][0]*xr[d][0] - xi[c][0]*xi[d][0]
                 + xr[c][1]*xr[d][1] - xi[c][1]*xi[d][1];
        acci[t] += xr[c][0]*xi[d][0] + xi[c][0]*xr[d][0]
                 + xr[c][1]*xi[d][1] + xi[c][1]*xr[d][1];
        t++;
      }
  }
  __shared__ float red[4][80];
  int wv = threadIdx.x >> 6, lane = threadIdx.x & 63;
  #pragma unroll
  for (int i = 0; i < 80; i++){
    float v = (i < 36) ? accr[i] : (i < 72) ? acci[i - 36] : nsq[i - 72];
    #pragma unroll
    for (int o = 32; o; o >>= 1) v += __shfl_xor(v, o, 64);
    if (lane == 0) red[wv][i] = v;
  }
  __syncthreads();
  if (threadIdx.x < 80){
    int i = threadIdx.x;
    PART[(long)(bh*8 + slab)*80 + i] = red[0][i] + red[1][i] + red[2][i] + red[3][i];
  }
}

__global__ void attn2f_kernel(const float* __restrict__ PART,
    const float* __restrict__ temp, float* __restrict__ ATT2){
  __shared__ float ssum[80];
  __shared__ float sar[64], sai[64];
  int bh = blockIdx.x;
  int t = threadIdx.x;
  if (t < 80){
    float s = 0.f;
    for (int i = 0; i < 8; i++) s += PART[(long)(bh*8 + i)*80 + t];
    ssum[t] = s;
  }
  __syncthreads();
  if (t >= 64) return;
  int lane = t;
  int c = lane >> 3, d = lane & 7;
  int lo = min(c, d), hi = max(c, d);
  int t2 = lo*8 - lo*(lo - 1)/2 + (hi - lo);
  float nnc = fmaxf(sqrtf(ssum[72 + c]), 1e-12f);
  float nnd = fmaxf(sqrtf(ssum[72 + d]), 1e-12f);
  float inv = temp[bh & 7] / (nnc * nnd);
  float ar = ssum[t2] * inv, ai = ssum[36 + t2] * inv;
  float m = ar;
  m = fmaxf(m, __shfl_xor(m, 1, 64)); m = fmaxf(m, __shfl_xor(m, 2, 64)); m = fmaxf(m, __shfl_xor(m, 4, 64));
  float e = __expf(ar - m);
  float su = e;
  su += __shfl_xor(su, 1, 64); su += __shfl_xor(su, 2, 64); su += __shfl_xor(su, 4, 64);
  ar = e / su;
  m = ai;
  m = fmaxf(m, __shfl_xor(m, 1, 64)); m = fmaxf(m, __shfl_xor(m, 2, 64)); m = fmaxf(m, __shfl_xor(m, 4, 64));
  e = __expf(ai - m);
  su = e;
  su += __shfl_xor(su, 1, 64); su += __shfl_xor(su, 2, 64); su += __shfl_xor(su, 4, 64);
  ai = e / su;
  sar[lane] = ar; sai[lane] = ai;
  __syncthreads();
  const float ct[8] = {1.f, 0.70710678f, 0.f, -0.70710678f, -1.f, -0.70710678f, 0.f, 0.70710678f};
  const float st[8] = {0.f, 0.70710678f, 1.f, 0.70710678f, 0.f, -0.70710678f, -1.f, -0.70710678f};
  int cp = c;
  float sr = 0.f, si = 0.f;
  #pragma unroll
  for (int cc = 0; cc < 8; cc++){
    int k = (cc * cp) & 7;
    float a = sar[cc*8 + d], b2 = sai[cc*8 + d];
    sr += ct[k]*a - st[k]*b2;
    si += ct[k]*b2 + st[k]*a;
  }
  float2 v; v.x = sr * 0.125f; v.y = si * 0.125f;
  ((float2*)ATT2)[bh*64 + lane] = v;
}

// gate hidden: H[b][j][px] = relu(bn(wa_j . f.real))  (bf16 f, ushort2 loads)
__global__ __launch_bounds__(256) void gateh_kernel(const unsigned short* __restrict__ Dre,
    const float* __restrict__ wa, const float* __restrict__ sbwa, float* __restrict__ H){
  int b = blockIdx.y;
  int px = (blockIdx.x*256 + threadIdx.x)*2;
  long base = (long)b * 64 * S + px;
  float h0a = 0.f, h1a = 0.f, h2a = 0.f, h3a = 0.f;
  float h0b = 0.f, h1b = 0.f, h2b = 0.f, h3b = 0.f;
  for (int ci = 0; ci < 64; ci++){
    ushort2 u = *(const ushort2*)(Dre + base + (long)ci*S);
    float xa = bf2f(u.x), xb = bf2f(u.y);
    float w0 = wa[ci], w1 = wa[64 + ci], w2 = wa[128 + ci], w3 = wa[192 + ci];
    h0a += w0*xa; h1a += w1*xa; h2a += w2*xa; h3a += w3*xa;
    h0b += w0*xb; h1b += w1*xb; h2b += w2*xb; h3b += w3*xb;
  }
  long ob = (long)b * 4 * S + px;
  float2 v;
  v.x = fmaxf(h0a*sbwa[0] + sbwa[4], 0.f); v.y = fmaxf(h0b*sbwa[0] + sbwa[4], 0.f);
  *(float2*)(H + ob) = v;
  v.x = fmaxf(h1a*sbwa[1] + sbwa[5], 0.f); v.y = fmaxf(h1b*sbwa[1] + sbwa[5], 0.f);
  *(float2*)(H + ob + S) = v;
  v.x = fmaxf(h2a*sbwa[2] + sbwa[6], 0.f); v.y = fmaxf(h2b*sbwa[2] + sbwa[6], 0.f);
  *(float2*)(H + ob + 2*S) = v;
  v.x = fmaxf(h3a*sbwa[3] + sbwa[7], 0.f); v.y = fmaxf(h3b*sbwa[3] + sbwa[7], 0.f);
  *(float2*)(H + ob + 3*S) = v;
}

// ---------------- small kernels ----------------
// mean over relu(sc*(P0+P1)+bb) per (b,ci) plane
__global__ __launch_bounds__(256) void mean2_kernel(const unsigned short* __restrict__ P0,
    const float* __restrict__ sbdc, float* __restrict__ M){
  int p = blockIdx.x;
  int ci = p & 127;
  float sc = sbdc[ci], bb = sbdc[128 + ci];
  long base = (long)p * S;
  float s = 0.f;
  for (int n = threadIdx.x*2; n < S; n += 512){
    ushort2 a0 = *(const ushort2*)(P0 + base + n);
    ushort2 a1 = *(const ushort2*)(P0 + APSTRIDE + base + n);
    s += fmaxf((bf2f(a0.x) + bf2f(a1.x))*sc + bb, 0.f)
       + fmaxf((bf2f(a0.y) + bf2f(a1.y))*sc + bb, 0.f);
  }
  #pragma unroll
  for (int o = 32; o; o >>= 1) s += __shfl_xor(s, o, 64);
  __shared__ float sm[4];
  if ((threadIdx.x & 63) == 0) sm[threadIdx.x >> 6] = s;
  __syncthreads();
  if (threadIdx.x == 0) M[p] = (sm[0] + sm[1] + sm[2] + sm[3]) * (1.0f/16384.0f);
}

// c5 (GAP 1x1 conv + bn_relu) and beff (wf tail contribution) fused: 1 block.
__global__ void c5beff_kernel(const float* __restrict__ W5, const float* __restrict__ sb5,
    const float* __restrict__ WF, const float* __restrict__ sbf,
    const float* __restrict__ M, float* __restrict__ BEFF){
  __shared__ float c5s[256];
  int t = threadIdx.x;
  if (t >= 256) return;
  int b = t >> 6, co = t & 63;
  float s = 0.f;
  for (int ci = 0; ci < 128; ci++) s += W5[co*128 + ci] * M[b*128 + ci];
  c5s[t] = fmaxf(s * sb5[co] + sb5[64 + co], 0.f);
  __syncthreads();
  float s2 = 0.f;
  for (int j = 0; j < 64; j++) s2 += WF[co*320 + 256 + j] * c5s[b*64 + j];
  BEFF[t] = s2 * sbf[co] + sbf[64 + co];
}

// output is FLOAT32 — write float4 (G input is bf16)
__global__ __launch_bounds__(256) void ob_kernel(const unsigned short* __restrict__ Tin,
    const float* __restrict__ wob, const float* __restrict__ bob, float* __restrict__ out){
  int b = blockIdx.y;
  int px = blockIdx.x*1024 + (threadIdx.x & 63)*4 + (threadIdx.x >> 6)*256;
  float b0 = bob[0];
  float4 a; a.x = b0; a.y = b0; a.z = b0; a.w = b0;
  for (int ci = 0; ci < 32; ci++){
    ushort4 v = *(const ushort4*)(Tin + ((long)b*32 + ci)*S + px);
    float w = wob[ci];
    a.x += w*bf2f(v.x); a.y += w*bf2f(v.y); a.z += w*bf2f(v.z); a.w += w*bf2f(v.w);
  }
  *(float4*)(out + (long)b*S + px) = a;
}

// ---------------- launch ----------------
extern "C" void kernel_launch(void* const* d_in, const int* in_sizes, int n_in,
                              void* d_out, int out_size, void* d_ws, size_t ws_size,
                              hipStream_t stream){
  float* ws = (float*)d_ws;
  Ptrs P;
  for (int i = 0; i < 43 && i < n_in; i++) P.p[i] = (const float*)d_in[i];
  float* out = (float*)d_out;

  float* H   = ws + O_H;

  unsigned short* AP0 = (unsigned short*)(ws + O_A);     // bf16 conv_dc partials
  unsigned short* FINB = (unsigned short*)(ws + O_FIN);  // bf16 c1|F2|F3|F4
  unsigned short* CCB  = (unsigned short*)(ws + O_CC);   // bf16 c2/c3/c4, later fused
  unsigned short* GB   = (unsigned short*)(ws + O_G);    // bf16 oa out
  unsigned short* DRE16 = (unsigned short*)(ws + O_DRE);
  unsigned short* DIM16 = (unsigned short*)(ws + O_DIMG);
  unsigned short* AB    = (unsigned short*)(ws + O_A);   // bf16 of|ol, overlays P0 after c1

  unsigned short* XT  = (unsigned short*)(ws + O_DRE);   // conv_dc input (pre-FFT)
  unsigned short* WHd = (unsigned short*)(ws + O_CC);
  unsigned short* WLd = (unsigned short*)(ws + O_CC + 147456);
  unsigned short* WB  = (unsigned short*)(ws + O_WB);
  unsigned short* WP  = (unsigned short*)(ws + O_WP);
  unsigned short* XP  = (unsigned short*)(ws + O_ERE);   // dil/oa input (pre-FFT per branch)

  prep_all_kernel<<<dim3(225), dim3(256), 0, stream>>>(P, ws, WHd, WLd, WB, WP);
  xpad_kernel<<<dim3(130, 4), dim3(256), 0, stream>>>(P.p[0], XT);

  // conv_dc K-split: 2048 blocks, single-bf16 weights, raw bf16 partials P0|P1
  convdc_split_kernel<<<dim3(2048), dim3(256), 0, stream>>>(XT, WHd, AP0);

  mean2_kernel<<<dim3(512), dim3(256), 0, stream>>>(AP0, ws + O_SBDC, ws + O_M);
  c5beff_kernel<<<dim3(1), dim3(256), 0, stream>>>(
      P.p[21], ws + O_SB5, P.p[33], ws + O_SBF, ws + O_M, ws + O_BEFF);

  // c1 -> FIN channels [0,64)  (MFMA, combine partials + dc bn_relu, bf16 out)
  conv1x1_mfma_kernel<0,4,2,1,1><<<dim3(512), dim3(256), 0, stream>>>(
      AP0, 128*S, WP, WP + 8192, ws + O_SB1, ws + O_SBDC, nullptr, 0, FINB, 256*S);

  for (int k = 0; k < 3; k++){
    const float* sb = ws + (k == 0 ? O_SB2 : k == 1 ? O_SB3 : O_SB4);
    const unsigned short* in2 = (k == 0) ? nullptr : FINB + (long)(64*k)*S;
    unsigned short* wh = WB + (k == 0 ? 0 : k == 1 ? 73728 : 147456);
    if (k == 0){
      xpad64_kernel<3,1><<<dim3(134, 4), dim3(256), 0, stream>>>(FINB, in2, 256*S, XP);
      conv3x3_mfma_kernel<3,2,64,1,0><<<dim3(512), dim3(256), 0, stream>>>(
          XP, wh, wh + 36864, sb, CCB);
    } else if (k == 1){
      xpad64_kernel<5,1><<<dim3(138, 4), dim3(256), 0, stream>>>(FINB, in2, 256*S, XP);
      conv3x3_mfma_kernel<5,2,64,1,0><<<dim3(512), dim3(256), 0, stream>>>(
          XP, wh, wh + 36864, sb, CCB);
    } else {
      xpad64_kernel<7,1><<<dim3(142, 4), dim3(256), 0, stream>>>(FINB, in2, 256*S, XP);
      conv3x3_mfma_kernel<7,2,64,1,0><<<dim3(512), dim3(256), 0, stream>>>(
          XP, wh, wh + 36864, sb, CCB);
    }

    // f = fft2(c) -> bf16 (fused per-plane 2D FFT; bf16 in)
    fft2_fwd_kernel<<<dim3(256), dim3(1024), 0, stream>>>(CCB, DRE16, DIM16);
    // attention stats
    gram_part_kernel<<<dim3(32, 8), dim3(256), 0, stream>>>(DRE16, DIM16, ws + O_PART);
    attn2f_kernel<<<dim3(32), dim3(128), 0, stream>>>(ws + O_PART, P.p[25], ws + O_ATT2);
    // gate hidden (4 ch) from f.real
    gateh_kernel<<<dim3(32, 4), dim3(256), 0, stream>>>(DRE16, P.p[27], ws + O_SBWA, H);
    // ol = |ifft2(sigmoid(wb.h+bwb) * f)| -> AB channels [64,128)
    ifft2_gate_abs_ol_kernel<<<dim3(256), dim3(1024), 0, stream>>>(
        DRE16, DIM16, H, P.p[31], P.p[32], AB);
    // of = |ifft_{c,n}(attn @ qkv)| -> AB channels [0,64)  (attn mix fused into load)
    ifft2_attn_abs_ofT_kernel<<<dim3(256), dim3(1024), 0, stream>>>(
        DRE16, DIM16, ws + O_ATT2, AB);
    // F_k = w_po @ concat(of, ol) + c  (MFMA, bf16 in, bf16 res, bf16 out)
    conv1x1_mfma_kernel<1,4,1,1,1><<<dim3(512), dim3(256), 0, stream>>>(
        AB, 128*S, WP + 16384, WP + 24576, nullptr, nullptr, CCB, 64*S,
        FINB + (long)(64*(k + 1))*S, 256*S);
  }

  // fused = bn_relu(w_f @ concat(c1,F2,F3,F4) + bias_eff(c5)) -> CCB bf16 (single-bf16 weights)
  conv1x1_mfma_kernel<2,8,1,1,0><<<dim3(512), dim3(256), 0, stream>>>(
      FINB, 256*S, WP + 32768, WP + 49152, ws + O_SBF, ws + O_BEFF, nullptr, 0, CCB, 64*S);
  xpad64_kernel<1,1><<<dim3(130, 4), dim3(256), 0, stream>>>(CCB, nullptr, 64*S, XP);
  conv3x3_mfma_kernel<1,2,32,1,1><<<dim3(512), dim3(256), 0, stream>>>(
      XP, WB + 221184, WB + 221184 + 18432, ws + O_SBOA, GB);
  ob_kernel<<<dim3(16, 4), dim3(256), 0, stream>>>(GB, P.p[41], P.p[42], out);
}

// Round 14
// 809.387 us; speedup vs baseline: 1.5145x; 1.5145x over previous
//
#include <hip/hip_runtime.h>

#define S 16384
#define PI_F 3.14159265358979f

struct Ptrs { const float* p[43]; };

// ---- workspace layout (float offsets) ----
enum : int {
  O_SBDC=0, O_SB1=256, O_SB2=512, O_SB3=768, O_SB4=1024, O_SB5=1280,
  O_SBWA=1536, O_SBF=1792, O_SBOA=2048,
  O_M=2304, O_C5=2816, O_NRM=3072, O_GRAM=3328, O_ATT2=7424, O_BEFF=11520,
  O_WB=16384,        // packed hi/lo bf16 weights for dil/oa convs
  O_PART=147456,     // gram/norm partials [256][80]
  O_H=180224,        // gate hidden H[4][4][S] (1 MB)
  O_WP=442368,       // packed hi/lo bf16 1x1 weights (w1|po|wf, 128 KB)
  O_A=524288,        // bf16 P0|P1 conv_dc partials; later AB bf16 overlays P0
  O_FIN=8912896,     // [4][256][S]  c1 | F2 | F3 | F4  (bf16)
  O_CC=25690112,     // [4][64][S]   c2/c3/c4 (bf16), later fused (bf16); dc weights early
  O_DRE=29884416, O_DIMG=34078720,   // f (complex, bf16 SoA); XT lives here pre-FFT
  O_ERE=38273024, O_EIM=42467328,    // scratch; dil/oa XP lives here transiently
  O_G=46661632       // [4][64][S]   later t (oa out, 32ch, bf16)
};
#define APSTRIDE 8388608L   // ushort elements per partial buffer [4][128][S]

typedef short bfrag __attribute__((ext_vector_type(8)));   // 8 bf16 = 4 VGPR
typedef float ffrag __attribute__((ext_vector_type(4)));   // 4 fp32 acc

__device__ __forceinline__ float bf2f(unsigned short u){
  union { unsigned int i; float f; } v; v.i = ((unsigned int)u) << 16; return v.f;
}
__device__ __forceinline__ unsigned short f2bf(float f){
  unsigned int x = __float_as_uint(f);
  unsigned int r = x + 0x7fffu + ((x >> 16) & 1u);
  return (unsigned short)(r >> 16);
}

// ---------------- merged param prep (prep_sb | wt | wtg | wtp) ----------------
// grid 225: [0,9) prep_sb, [9,137) wt, [137,201) wtg, [201,225) wtp
__global__ void prep_all_kernel(Ptrs P, float* ws,
    unsigned short* __restrict__ WHd, unsigned short* __restrict__ WLd,
    unsigned short* __restrict__ WB, unsigned short* __restrict__ WP){
  int bid = blockIdx.x;
  int tid = threadIdx.x;
  if (bid < 9){
    const float r = rsqrtf(1.0f + 1e-5f);
    int bi=0, si=0, oi=0, C=0, dst=0;
    switch (bid){
      case 0: bi=2; si=3; oi=4; C=128; dst=O_SBDC; break;
      case 1: bi=6; si=7; oi=8; C=64; dst=O_SB1; break;
      case 2: bi=10; si=11; oi=12; C=64; dst=O_SB2; break;
      case 3: bi=14; si=15; oi=16; C=64; dst=O_SB3; break;
      case 4: bi=18; si=19; oi=20; C=64; dst=O_SB4; break;
      case 5: bi=22; si=23; oi=24; C=64; dst=O_SB5; break;
      case 6: bi=28; si=29; oi=30; C=4;  dst=O_SBWA; break;
      case 7: bi=34; si=35; oi=36; C=64; dst=O_SBF; break;
      default: bi=38; si=39; oi=40; C=32; dst=O_SBOA; break;
    }
    for (int c = tid; c < C; c += 256){
      float bb = P.p[bi][c], ss = P.p[si][c], oo = P.p[oi][c];
      float sc = ss * r;
      ws[dst + c] = sc;
      ws[dst + C + c] = bb * sc + oo;
    }
    return;
  }
  if (bid < 137){
    const float* w = P.p[1];
    for (int e = (bid - 9)*256 + tid; e < 294912; e += 128*256){
      int c32 = e & 31, co = (e >> 5) & 127, kc = (e >> 12) & 7, sh = e >> 15;
      int ky = sh / 3, kx = sh - ky*3;
      int ci = kc*32 + c32;
      float v = w[((long)(co*256 + ci)*3 + ky)*3 + kx];
      unsigned short h = f2bf(v);
      WHd[e] = h;
      WLd[e] = f2bf(v - bf2f(h));
    }
    return;
  }
  if (bid < 201){
    int lb = bid - 137;
    int gx = lb & 15, gy = lb >> 4;
    const float* w; int cout; long off;
    switch (gy){
      case 0: w = P.p[9];  cout = 64; off = 0;      break;
      case 1: w = P.p[13]; cout = 64; off = 73728;  break;
      case 2: w = P.p[17]; cout = 64; off = 147456; break;
      default: w = P.p[37]; cout = 32; off = 221184; break;
    }
    int total = 576*cout;
    unsigned short* WH = WB + off;
    unsigned short* WL = WH + total;
    for (int e = gx*256 + tid; e < total; e += 16*256){
      int c32 = e & 31;
      int co = (e >> 5) & (cout - 1);
      int kc = (e / (32*cout)) & 1;
      int sh = e / (64*cout);
      int ky = sh/3, kx = sh - ky*3;
      int ci = kc*32 + c32;
      float v = w[((long)(co*64 + ci)*3 + ky)*3 + kx];
      unsigned short h = f2bf(v);
      WH[e] = h;
      WL[e] = f2bf(v - bf2f(h));
    }
    return;
  }
  {
    int lb = bid - 201;
    int gx = lb & 7, gy = lb >> 3;
    const float* w; int KC, wstr; long off;
    switch (gy){
      case 0: w = P.p[5];  KC = 4; wstr = 128; off = 0;     break;
      case 1: w = P.p[26]; KC = 4; wstr = 128; off = 16384; break;
      default: w = P.p[33]; KC = 8; wstr = 320; off = 32768; break;
    }
    int total = KC*64*32;
    unsigned short* WH = WP + off;
    unsigned short* WL = WH + total;
    for (int e = gx*256 + tid; e < total; e += 8*256){
      int c32 = e & 31, co = (e >> 5) & 63, kc = e >> 11;
      float v = w[(long)co*wstr + kc*32 + c32];
      unsigned short h = f2bf(v);
      WH[e] = h;
      WL[e] = f2bf(v - bf2f(h));
    }
  }
}

// ---------------- conv_dc input prepack ----------------
__global__ __launch_bounds__(256) void xpad_kernel(const float* __restrict__ x,
    unsigned short* __restrict__ XT){
  int yy = blockIdx.x, b = blockIdx.y;
  long obase = ((long)(b*130) + yy) * (130L*256);
  int tid = threadIdx.x;
  if (yy == 0 || yy == 129){
    uint4 z; z.x=0; z.y=0; z.z=0; z.w=0;
    for (int i = tid; i < 130*256/8; i += 256)
      *(uint4*)(XT + obase + (long)i*8) = z;
    return;
  }
  __shared__ float LT[64][129];
  int y = yy - 1;
  for (int c0 = 0; c0 < 256; c0 += 64){
    for (int idx = tid; idx < 64*128; idx += 256){
      int ci = idx >> 7, xx = idx & 127;
      LT[ci][xx] = x[((long)(b*256 + c0 + ci)*128 + y)*128 + xx];
    }
    __syncthreads();
    for (int idx = tid; idx < 128*16; idx += 256){
      int xp = idx >> 4, c4 = (idx & 15)*4;
      ushort4 v;
      v.x = f2bf(LT[c4][xp]);   v.y = f2bf(LT[c4+1][xp]);
      v.z = f2bf(LT[c4+2][xp]); v.w = f2bf(LT[c4+3][xp]);
      *(ushort4*)(XT + obase + (long)(xp+1)*256 + c0 + c4) = v;
    }
    __syncthreads();
  }
  if (tid < 64){
    ushort4 z; z.x=0; z.y=0; z.z=0; z.w=0;
    *(ushort4*)(XT + obase + tid*4) = z;
    *(ushort4*)(XT + obase + 129L*256 + tid*4) = z;
  }
}

// pad+pack 64ch input; BF16IN=1: in1/in2 bf16 planes (sum), else fp32 (in2 unused)
template<int DIL, int BF16IN>
__global__ __launch_bounds__(256) void xpad64_kernel(const void* __restrict__ in1,
    const void* __restrict__ in2, long in_bs, unsigned short* __restrict__ XP){
  constexpr int TW = 128 + 2*DIL;
  int yy = blockIdx.x, b = blockIdx.y;
  long obase = (long)(b*TW + yy) * TW * 64;
  int tid = threadIdx.x;
  if (yy < DIL || yy >= 128 + DIL){
    uint4 z; z.x=0; z.y=0; z.z=0; z.w=0;
    for (int i = tid; i < TW*8; i += 256)
      *(uint4*)(XP + obase + (long)i*8) = z;
    return;
  }
  __shared__ float LT[64][129];
  int y = yy - DIL;
  if (BF16IN){
    const unsigned short* p1 = (const unsigned short*)in1 + (long)b*in_bs + (long)y*128;
    const unsigned short* p2 = in2 ? (const unsigned short*)in2 + (long)b*in_bs + (long)y*128 : nullptr;
    for (int idx = tid; idx < 64*64; idx += 256){
      int ci = idx >> 6, x2 = (idx & 63)*2;
      ushort2 u1 = *(const ushort2*)(p1 + (long)ci*S + x2);
      float a0 = bf2f(u1.x), a1 = bf2f(u1.y);
      if (p2){
        ushort2 u2 = *(const ushort2*)(p2 + (long)ci*S + x2);
        a0 += bf2f(u2.x); a1 += bf2f(u2.y);
      }
      LT[ci][x2] = a0; LT[ci][x2+1] = a1;
    }
  } else {
    const float* p1 = (const float*)in1 + (long)b*in_bs + (long)y*128;
    for (int idx = tid; idx < 64*128; idx += 256){
      int ci = idx >> 7, xx = idx & 127;
      LT[ci][xx] = p1[(long)ci*S + xx];
    }
  }
  __syncthreads();
  for (int i = tid; i < 2*DIL*16; i += 256){
    int side = i / (DIL*16);
    int r = i - side*(DIL*16);
    int xcol = side ? (128 + DIL + (r >> 4)) : (r >> 4);
    ushort4 z; z.x=0; z.y=0; z.z=0; z.w=0;
    *(ushort4*)(XP + obase + (long)xcol*64 + (r & 15)*4) = z;
  }
  for (int idx = tid; idx < 128*16; idx += 256){
    int xp = idx >> 4, c4 = (idx & 15)*4;
    ushort4 v;
    v.x = f2bf(LT[c4][xp]);   v.y = f2bf(LT[c4+1][xp]);
    v.z = f2bf(LT[c4+2][xp]); v.w = f2bf(LT[c4+3][xp]);
    *(ushort4*)(XP + obase + (long)(xp + DIL)*64 + c4) = v;
  }
}

// ---------------- conv_dc K-split: raw bf16 partials, 2048 blocks ----------------
// Single bf16 weights (round-9 config: 67us best measured).
__global__ __launch_bounds__(256) void convdc_split_kernel(
    const unsigned short* __restrict__ XP,
    const unsigned short* __restrict__ WH,
    unsigned short* __restrict__ out){
  constexpr int CIN = 256, TW = 130, LDA = 36, NSTG = 3;
  __shared__ unsigned short As[2][TW*LDA];
  int bid = blockIdx.x;
  int y = (bid & 7)*16 + ((bid >> 3) & 15);
  int b = (bid >> 7) & 3;
  int n2 = (bid >> 9) & 1;
  int ks = bid >> 10;
  int tid = threadIdx.x, wv = tid >> 6, lane = tid & 63;
  int mhalf = wv & 1, nhalf = wv >> 1;
  int px0 = mhalf*64;
  ffrag acc[4][2];
  #pragma unroll
  for (int i = 0; i < 4; i++)
    #pragma unroll
    for (int j = 0; j < 2; j++)
      #pragma unroll
      for (int r = 0; r < 4; r++) acc[i][j][r] = 0.f;
  int kq = (lane >> 4)*8, rown = lane & 15;
  int sx = tid >> 2, sq = tid & 3;
  int cobase = n2*64 + nhalf*32;
  {
    long rowbase = ((long)(b*TW + y))*TW*CIN + (ks*4)*32 + sq*8;
    #pragma unroll
    for (int t = 0; t < NSTG; t++){
      int x = sx + 64*t;
      int xc = x < TW ? x : TW - 1;
      uint4 v = *(const uint4*)(XP + rowbase + (long)xc*CIN);
      if (x < TW) *(uint4*)&As[0][x*LDA + sq*8] = v;
    }
  }
  __syncthreads();
  for (int s = 0; s < 12; s++){
    int cur = s & 1;
    int ky = s >> 2, kcl = s & 3;
    int kc = ks*4 + kcl;
    int s2 = (s + 1 < 12) ? s + 1 : s;
    int ky2 = s2 >> 2, kc2 = ks*4 + (s2 & 3);
    uint4 pre[NSTG];
    {
      long rowbase = ((long)(b*TW + y + ky2))*TW*CIN + kc2*32 + sq*8;
      #pragma unroll
      for (int t = 0; t < NSTG; t++){
        int x = sx + 64*t;
        int xc = x < TW ? x : TW - 1;
        pre[t] = *(const uint4*)(XP + rowbase + (long)xc*CIN);
      }
    }
    #pragma unroll
    for (int kx = 0; kx < 3; kx++){
      int step = (ky*3 + kx)*8 + kc;
      bfrag bhf[2];
      #pragma unroll
      for (int j = 0; j < 2; j++){
        long wb = ((long)step*128 + cobase + j*16 + rown)*32 + kq;
        bhf[j] = *(const bfrag*)(WH + wb);
      }
      bfrag af[4];
      #pragma unroll
      for (int i = 0; i < 4; i++){
        int x = px0 + i*16 + rown + kx;
        af[i] = *(const bfrag*)&As[cur][x*LDA + kq];
      }
      #pragma unroll
      for (int i = 0; i < 4; i++)
        #pragma unroll
        for (int j = 0; j < 2; j++)
          acc[i][j] = __builtin_amdgcn_mfma_f32_16x16x32_bf16(af[i], bhf[j], acc[i][j], 0, 0, 0);
    }
    #pragma unroll
    for (int t = 0; t < NSTG; t++){
      int x = sx + 64*t;
      if (x < TW) *(uint4*)&As[cur ^ 1][x*LDA + sq*8] = pre[t];
    }
    __syncthreads();
  }
  unsigned short* dst = out + ks*APSTRIDE;
  #pragma unroll
  for (int i = 0; i < 4; i++){
    int pixel = px0 + i*16 + (lane >> 4)*4;
    #pragma unroll
    for (int j = 0; j < 2; j++){
      int co = cobase + j*16 + (lane & 15);
      ushort4 w;
      w.x = f2bf(acc[i][j][0]); w.y = f2bf(acc[i][j][1]);
      w.z = f2bf(acc[i][j][2]); w.w = f2bf(acc[i][j][3]);
      *(ushort4*)(dst + ((long)(b*128 + co))*S + y*128 + pixel) = w;
    }
  }
}

// ---------------- 3x3 conv via MFMA implicit GEMM ------
// HILO=1: hi/lo dual-MFMA weights; HILO=0: single bf16 weights (half MFMA+traffic).
template<int DIL, int KC, int NBLK, int BF16OUT, int HILO>
__global__ __launch_bounds__(256) void conv3x3_mfma_kernel(
    const unsigned short* __restrict__ XP,
    const unsigned short* __restrict__ WH, const unsigned short* __restrict__ WL,
    const float* __restrict__ scbi, void* __restrict__ out){
  constexpr int CIN = KC*32;
  constexpr int TW = 128 + 2*DIL;
  constexpr int NJ = NBLK/32;
  constexpr int LDA = 36;
  constexpr int NSTG = (TW + 63)/64;
  constexpr int NS = 3*KC;
  __shared__ unsigned short As[2][TW*LDA];
  int bid = blockIdx.x;
  int y = (bid & 7)*16 + ((bid >> 3) & 15);
  int b = (bid >> 7) & 3;
  int n2 = bid >> 9;
  int nb = gridDim.x >> 9; if (nb == 0) nb = 1;
  int coutTotal = nb * NBLK;
  int tid = threadIdx.x, wv = tid >> 6, lane = tid & 63;
  int mhalf = wv & 1, nhalf = wv >> 1;
  int px0 = mhalf*64;
  ffrag acc[4][NJ];
  #pragma unroll
  for (int i = 0; i < 4; i++)
    #pragma unroll
    for (int j = 0; j < NJ; j++)
      #pragma unroll
      for (int r = 0; r < 4; r++) acc[i][j][r] = 0.f;

  int kq = (lane >> 4)*8, rown = lane & 15;
  int sx = tid >> 2, sq = tid & 3;
  int cobase = n2*NBLK + nhalf*(NBLK/2);

  {
    long rowbase = ((long)(b*TW + y))*TW*CIN + sq*8;
    #pragma unroll
    for (int t = 0; t < NSTG; t++){
      int x = sx + 64*t;
      int xc = x < TW ? x : TW - 1;
      uint4 v = *(const uint4*)(XP + rowbase + (long)xc*CIN);
      if (x < TW) *(uint4*)&As[0][x*LDA + sq*8] = v;
    }
  }
  __syncthreads();

  for (int s = 0; s < NS; s++){
    int cur = s & 1;
    int ky = s / KC, kc = s - ky*KC;
    int s2 = (s + 1 < NS) ? s + 1 : s;
    int ky2 = s2 / KC, kc2 = s2 - ky2*KC;
    uint4 pre[NSTG];
    {
      long rowbase = ((long)(b*TW + y + ky2*DIL))*TW*CIN + kc2*32 + sq*8;
      #pragma unroll
      for (int t = 0; t < NSTG; t++){
        int x = sx + 64*t;
        int xc = x < TW ? x : TW - 1;
        pre[t] = *(const uint4*)(XP + rowbase + (long)xc*CIN);
      }
    }
    #pragma unroll
    for (int kx = 0; kx < 3; kx++){
      int step = (ky*3 + kx)*KC + kc;
      bfrag bhf[NJ], blf[NJ];
      #pragma unroll
      for (int j = 0; j < NJ; j++){
        long wb = ((long)step*coutTotal + cobase + j*16 + rown)*32 + kq;
        bhf[j] = *(const bfrag*)(WH + wb);
        if (HILO) blf[j] = *(const bfrag*)(WL + wb);
      }
      bfrag af[4];
      #pragma unroll
      for (int i = 0; i < 4; i++){
        int x = px0 + i*16 + rown + kx*DIL;
        af[i] = *(const bfrag*)&As[cur][x*LDA + kq];
      }
      #pragma unroll
      for (int i = 0; i < 4; i++)
        #pragma unroll
        for (int j = 0; j < NJ; j++){
          if (HILO)
            acc[i][j] = __builtin_amdgcn_mfma_f32_16x16x32_bf16(af[i], blf[j], acc[i][j], 0, 0, 0);
          acc[i][j] = __builtin_amdgcn_mfma_f32_16x16x32_bf16(af[i], bhf[j], acc[i][j], 0, 0, 0);
        }
    }
    #pragma unroll
    for (int t = 0; t < NSTG; t++){
      int x = sx + 64*t;
      if (x < TW) *(uint4*)&As[cur ^ 1][x*LDA + sq*8] = pre[t];
    }
    __syncthreads();
  }
  #pragma unroll
  for (int i = 0; i < 4; i++){
    int pixel = px0 + i*16 + (lane >> 4)*4;
    #pragma unroll
    for (int j = 0; j < NJ; j++){
      int co = cobase + j*16 + (lane & 15);
      float sc = scbi[co], bb = scbi[coutTotal + co];
      long ooff = ((long)(b*coutTotal + co))*S + y*128 + pixel;
      if (BF16OUT){
        ushort4 w;
        w.x = f2bf(fmaxf(acc[i][j][0]*sc + bb, 0.f));
        w.y = f2bf(fmaxf(acc[i][j][1]*sc + bb, 0.f));
        w.z = f2bf(fmaxf(acc[i][j][2]*sc + bb, 0.f));
        w.w = f2bf(fmaxf(acc[i][j][3]*sc + bb, 0.f));
        *(ushort4*)((unsigned short*)out + ooff) = w;
      } else {
        float* op = (float*)out + ooff;
        #pragma unroll
        for (int r = 0; r < 4; r++)
          op[r] = fmaxf(acc[i][j][r]*sc + bb, 0.f);
      }
    }
  }
}

// ---------------- 1x1 conv via MFMA ----
// B (weights) global-direct. A double-buffered in LDS, one barrier per kc.
// MODE 0: bn_relu | 1: +residual | 2: per-(b,co) bias.
// BF16IN: 0 fp32 | 1 bf16 | 2 combine bf16 partials P0/P1 w/ dc bn_relu (beff table).
// HILO=0: single bf16 weights.
template<int MODE, int KC, int BF16IN, int BF16OUT, int HILO>
__global__ __launch_bounds__(256) void conv1x1_mfma_kernel(
    const void* __restrict__ inv, long in_bs,
    const unsigned short* __restrict__ WH, const unsigned short* __restrict__ WL,
    const float* __restrict__ scbi, const float* __restrict__ beff,
    const unsigned short* __restrict__ res, long res_bs,
    void* __restrict__ outv, long out_bs){
  constexpr int LDA = 36;
  __shared__ unsigned short Als[2][128*LDA];
  int bid = blockIdx.x;
  int y = (bid & 7)*16 + ((bid >> 3) & 15);
  int b = bid >> 7;
  int tid = threadIdx.x, wv = tid >> 6, lane = tid & 63;
  int mt0 = (wv & 1)*4, nt0 = (wv >> 1)*2;
  ffrag acc[4][2];
  #pragma unroll
  for (int i = 0; i < 4; i++)
    #pragma unroll
    for (int j = 0; j < 2; j++)
      #pragma unroll
      for (int r = 0; r < 4; r++) acc[i][j][r] = 0.f;
  int pq = tid & 31, cg = tid >> 5;
  int kq = (lane >> 4)*8, rown = lane & 15;
  const float* ibf = (const float*)inv + (long)b*in_bs + y*128;
  const unsigned short* ibs = (const unsigned short*)inv + (long)b*in_bs + y*128;
  unsigned short a[16];
  #pragma unroll
  for (int cc = 0; cc < 4; cc++)
    #pragma unroll
    for (int i = 0; i < 4; i++){
      long off = (long)(cg*4 + cc)*S + pq + 32*i;
      if (BF16IN == 1) a[cc*4 + i] = ibs[off];
      else if (BF16IN == 2){
        float v = bf2f(ibs[off]) + bf2f(ibs[off + APSTRIDE]);
        int ci = cg*4 + cc;
        a[cc*4 + i] = f2bf(fmaxf(v*beff[ci] + beff[128 + ci], 0.f));
      } else a[cc*4 + i] = f2bf(ibf[off]);
    }
  #pragma unroll
  for (int i = 0; i < 4; i++){
    ushort4 v;
    v.x = a[0 + i];  v.y = a[4 + i];
    v.z = a[8 + i];  v.w = a[12 + i];
    *(ushort4*)&Als[0][(pq + 32*i)*LDA + cg*4] = v;
  }
  __syncthreads();
  for (int kc = 0; kc < KC; kc++){
    int cur = kc & 1;
    int kcn = (kc + 1 < KC) ? kc + 1 : kc;
    #pragma unroll
    for (int cc = 0; cc < 4; cc++)
      #pragma unroll
      for (int i = 0; i < 4; i++){
        long off = (long)(kcn*32 + cg*4 + cc)*S + pq + 32*i;
        if (BF16IN == 1) a[cc*4 + i] = ibs[off];
        else if (BF16IN == 2){
          float v = bf2f(ibs[off]) + bf2f(ibs[off + APSTRIDE]);
          int ci = kcn*32 + cg*4 + cc;
          a[cc*4 + i] = f2bf(fmaxf(v*beff[ci] + beff[128 + ci], 0.f));
        } else a[cc*4 + i] = f2bf(ibf[off]);
      }
    bfrag af[4], bhf[2], blf[2];
    #pragma unroll
    for (int j = 0; j < 2; j++){
      long wb = ((long)kc*64 + (nt0 + j)*16 + rown)*32 + kq;
      bhf[j] = *(const bfrag*)(WH + wb);
      if (HILO) blf[j] = *(const bfrag*)(WL + wb);
    }
    #pragma unroll
    for (int i = 0; i < 4; i++)
      af[i] = *(const bfrag*)&Als[cur][((mt0 + i)*16 + rown)*LDA + kq];
    #pragma unroll
    for (int i = 0; i < 4; i++)
      #pragma unroll
      for (int j = 0; j < 2; j++){
        if (HILO)
          acc[i][j] = __builtin_amdgcn_mfma_f32_16x16x32_bf16(af[i], blf[j], acc[i][j], 0, 0, 0);
        acc[i][j] = __builtin_amdgcn_mfma_f32_16x16x32_bf16(af[i], bhf[j], acc[i][j], 0, 0, 0);
      }
    #pragma unroll
    for (int i = 0; i < 4; i++){
      ushort4 v;
      v.x = a[0 + i];  v.y = a[4 + i];
      v.z = a[8 + i];  v.w = a[12 + i];
      *(ushort4*)&Als[cur ^ 1][(pq + 32*i)*LDA + cg*4] = v;
    }
    __syncthreads();
  }
  #pragma unroll
  for (int i = 0; i < 4; i++){
    int pixel = (mt0 + i)*16 + (lane >> 4)*4;
    #pragma unroll
    for (int j = 0; j < 2; j++){
      int co = (nt0 + j)*16 + (lane & 15);
      long ooff = (long)b*out_bs + (long)co*S + y*128 + pixel;
      float vv[4];
      if (MODE == 1){
        ushort4 rv = *(const ushort4*)(res + (long)b*res_bs + (long)co*S + y*128 + pixel);
        vv[0] = acc[i][j][0] + bf2f(rv.x);
        vv[1] = acc[i][j][1] + bf2f(rv.y);
        vv[2] = acc[i][j][2] + bf2f(rv.z);
        vv[3] = acc[i][j][3] + bf2f(rv.w);
      } else if (MODE == 0){
        #pragma unroll
        for (int r = 0; r < 4; r++)
          vv[r] = fmaxf(acc[i][j][r]*scbi[co] + scbi[64 + co], 0.f);
      } else {
        #pragma unroll
        for (int r = 0; r < 4; r++)
          vv[r] = fmaxf(acc[i][j][r]*scbi[co] + beff[b*64 + co], 0.f);
      }
      if (BF16OUT){
        ushort4 w;
        w.x = f2bf(vv[0]); w.y = f2bf(vv[1]); w.z = f2bf(vv[2]); w.w = f2bf(vv[3]);
        *(ushort4*)((unsigned short*)outv + ooff) = w;
      } else {
        float* op = (float*)outv + ooff;
        #pragma unroll
        for (int r = 0; r < 4; r++) op[r] = vv[r];
      }
    }
  }
}

// ---------------- FFT-128 with hoisted lane twiddles ----------------
__device__ __forceinline__ void fft128_mk_tw(float (&tws)[8], float (&twc)[8],
                                             float sign, int lane){
  float a0 = sign * (2.0f*PI_F/128.0f) * (float)lane;
  __sincosf(a0, &tws[0], &twc[0]);
  int i = 1;
  #pragma unroll
  for (int h = 32; h >= 1; h >>= 1, i++){
    int j = lane & (h - 1);
    float a = sign * (2.0f*PI_F/128.0f) * (float)(j * (64/h));
    __sincosf(a, &tws[i], &twc[i]);
  }
}

__device__ __forceinline__ void fft128(float& z0r, float& z0i, float& z1r, float& z1i,
    const float (&tws)[8], const float (&twc)[8], int lane){
  {
    float ar = z0r, ai = z0i, br = z1r, bi = z1i;
    z0r = ar + br; z0i = ai + bi;
    float dr = ar - br, di = ai - bi;
    float s = tws[0], c = twc[0];
    z1r = dr*c - di*s; z1i = dr*s + di*c;
  }
  int idx = 1;
  #pragma unroll
  for (int h = 32; h >= 1; h >>= 1, idx++){
    float s = tws[idx], c = twc[idx];
    bool up = (lane & h) != 0;
    float pr, pi, nr, ni;
    pr = __shfl_xor(z0r, h, 64); pi = __shfl_xor(z0i, h, 64);
    if (!up){ nr = z0r + pr; ni = z0i + pi; }
    else { float dr = pr - z0r, di = pi - z0i; nr = dr*c - di*s; ni = dr*s + di*c; }
    z0r = nr; z0i = ni;
    pr = __shfl_xor(z1r, h, 64); pi = __shfl_xor(z1i, h, 64);
    if (!up){ nr = z1r + pr; ni = z1i + pi; }
    else { float dr = pr - z1r, di = pi - z1i; nr = dr*c - di*s; ni = dr*s + di*c; }
    z1r = nr; z1i = ni;
  }
}

// ---------------- fused per-plane 2D FFT kernels ----------------

// fwd fft2: bf16 plane -> bf16 D[yfreq][xfreq]
__global__ __launch_bounds__(1024) void fft2_fwd_kernel(const unsigned short* __restrict__ in,
    unsigned short* __restrict__ outRe, unsigned short* __restrict__ outIm){
  __shared__ float lre[128][129];
  __shared__ float lim[128][129];
  int plane = blockIdx.x;
  int tid = threadIdx.x, wv = tid >> 6, lane = tid & 63;
  long pbase = (long)plane * S;
  for (int i = tid; i < S/4; i += 1024){
    int px = i*4; int r = px >> 7, c = px & 127;
    ushort4 v = *(const ushort4*)(in + pbase + px);
    lre[r][c] = bf2f(v.x); lre[r][c+1] = bf2f(v.y);
    lre[r][c+2] = bf2f(v.z); lre[r][c+3] = bf2f(v.w);
  }
  float tws[8], twc[8];
  fft128_mk_tw(tws, twc, -1.0f, lane);
  __syncthreads();
  #pragma unroll
  for (int rr = 0; rr < 8; rr++){
    int r = wv*8 + rr;
    float z0r = lre[r][lane], z0i = 0.f;
    float z1r = lre[r][lane + 64], z1i = 0.f;
    fft128(z0r, z0i, z1r, z1i, tws, twc, lane);
    int k = __brev(lane) >> 25;
    lre[r][k] = z0r;     lim[r][k] = z0i;
    lre[r][k+1] = z1r;   lim[r][k+1] = z1i;
  }
  __syncthreads();
  #pragma unroll
  for (int cc = 0; cc < 8; cc++){
    int c = wv*8 + cc;
    float z0r = lre[lane][c], z0i = lim[lane][c];
    float z1r = lre[lane + 64][c], z1i = lim[lane + 64][c];
    fft128(z0r, z0i, z1r, z1i, tws, twc, lane);
    int k = __brev(lane) >> 25;
    lre[k][c] = z0r;     lim[k][c] = z0i;
    lre[k+1][c] = z1r;   lim[k+1][c] = z1i;
  }
  __syncthreads();
  for (int i = tid; i < S/2; i += 1024){
    int px = i*2; int r = px >> 7, c = px & 127;
    ushort2 vr, vi;
    vr.x = f2bf(lre[r][c]); vr.y = f2bf(lre[r][c+1]);
    vi.x = f2bf(lim[r][c]); vi.y = f2bf(lim[r][c+1]);
    *(ushort2*)(outRe + pbase + px) = vr;
    *(ushort2*)(outIm + pbase + px) = vi;
  }
}

// ol: gate-premul + col IFFT + row IFFT + abs -> AB[64..128)
__global__ __launch_bounds__(1024) void ifft2_gate_abs_ol_kernel(
    const unsigned short* __restrict__ Dre, const unsigned short* __restrict__ Dim,
    const float* __restrict__ H, const float* __restrict__ wb, const float* __restrict__ bwb,
    unsigned short* __restrict__ AB){
  __shared__ float lre[128][129];
  __shared__ float lim[128][129];
  int plane = blockIdx.x;             // b*64 + ch
  int b = plane >> 6, ch = plane & 63;
  int tid = threadIdx.x, wv = tid >> 6, lane = tid & 63;
  long pbase = (long)plane * S;
  float w0 = wb[ch*4], w1 = wb[ch*4+1], w2 = wb[ch*4+2], w3 = wb[ch*4+3];
  float bw = bwb[ch];
  const float* Hb = H + (long)b*4*S;
  for (int i = tid; i < S/2; i += 1024){
    int px = i*2;
    float2 h0 = *(const float2*)(Hb + px);
    float2 h1 = *(const float2*)(Hb + S + px);
    float2 h2 = *(const float2*)(Hb + 2*S + px);
    float2 h3 = *(const float2*)(Hb + 3*S + px);
    ushort2 ur = *(const ushort2*)(Dre + pbase + px);
    ushort2 ui = *(const ushort2*)(Dim + pbase + px);
    float hva = bw + w0*h0.x + w1*h1.x + w2*h2.x + w3*h3.x;
    float hvb = bw + w0*h0.y + w1*h1.y + w2*h2.y + w3*h3.y;
    float ga = 1.0f / (1.0f + __expf(-hva));
    float gb = 1.0f / (1.0f + __expf(-hvb));
    int r = px >> 7, c = px & 127;
    lre[r][c]   = bf2f(ur.x) * ga;  lim[r][c]   = bf2f(ui.x) * ga;
    lre[r][c+1] = bf2f(ur.y) * gb;  lim[r][c+1] = bf2f(ui.y) * gb;
  }
  float tws[8], twc[8];
  fft128_mk_tw(tws, twc, 1.0f, lane);
  __syncthreads();
  #pragma unroll
  for (int cc = 0; cc < 8; cc++){
    int c = wv*8 + cc;
    float z0r = lre[lane][c], z0i = lim[lane][c];
    float z1r = lre[lane + 64][c], z1i = lim[lane + 64][c];
    fft128(z0r, z0i, z1r, z1i, tws, twc, lane);
    int k = __brev(lane) >> 25;
    lre[k][c] = z0r;     lim[k][c] = z0i;
    lre[k+1][c] = z1r;   lim[k+1][c] = z1i;
  }
  __syncthreads();
  unsigned short* out = AB + ((long)(b*128 + 64 + ch)) * S;
  #pragma unroll
  for (int rr = 0; rr < 8; rr++){
    int r = wv*8 + rr;
    float z0r = lre[r][lane], z0i = lim[r][lane];
    float z1r = lre[r][lane + 64], z1i = lim[r][lane + 64];
    fft128(z0r, z0i, z1r, z1i, tws, twc, lane);
    int k = __brev(lane) >> 25;
    ushort2 v;
    v.x = f2bf(sqrtf(z0r*z0r + z0i*z0i) * (1.0f/16384.0f));
    v.y = f2bf(sqrtf(z1r*z1r + z1i*z1i) * (1.0f/16384.0f));
    *(ushort2*)(out + (long)r*128 + k) = v;
  }
}

// of: attn channel-mix + col IFFT + 4-step twiddle + row IFFT + abs + transposed store
// XCD-swizzled block decode: bid = cp*32 + bh so all 8 cp-blocks of one bh share
// an XCD (XCD = bid%8 = bh%8) -> D planes L2-resident once per XCD (T1).
__global__ __launch_bounds__(1024) void ifft2_attn_abs_ofT_kernel(
    const unsigned short* __restrict__ Dre, const unsigned short* __restrict__ Dim,
    const float* __restrict__ ATT2, unsigned short* __restrict__ AB){
  __shared__ float lre[128][129];
  __shared__ float lim[128][129];
  int bid = blockIdx.x;
  int bh = bid & 31;                  // b*8 + h  (XCD = bh%8 for all cp)
  int cp = bid >> 5;                  // 0..7
  int plane = bh*8 + cp;              // b*64 + h*8 + cp
  int b = plane >> 6, ch = plane & 63;
  int tid = threadIdx.x, wv = tid >> 6, lane = tid & 63;
  long hbase = (long)bh * 8 * S;
  float wr[8], wi[8];
  #pragma unroll
  for (int d = 0; d < 8; d++){
    wr[d] = ATT2[bh*128 + (cp*8 + d)*2];
    wi[d] = ATT2[bh*128 + (cp*8 + d)*2 + 1];
  }
  for (int i = tid; i < S/4; i += 1024){
    int px = i*4;
    float sr0=0.f, si0=0.f, sr1=0.f, si1=0.f, sr2=0.f, si2=0.f, sr3=0.f, si3=0.f;
    #pragma unroll
    for (int d = 0; d < 8; d++){
      ushort4 ur = *(const ushort4*)(Dre + hbase + (long)d*S + px);
      ushort4 ui = *(const ushort4*)(Dim + hbase + (long)d*S + px);
      float xr0 = bf2f(ur.x), xi0 = bf2f(ui.x);
      float xr1 = bf2f(ur.y), xi1 = bf2f(ui.y);
      float xr2 = bf2f(ur.z), xi2 = bf2f(ui.z);
      float xr3 = bf2f(ur.w), xi3 = bf2f(ui.w);
      sr0 += wr[d]*xr0 - wi[d]*xi0;  si0 += wr[d]*xi0 + wi[d]*xr0;
      sr1 += wr[d]*xr1 - wi[d]*xi1;  si1 += wr[d]*xi1 + wi[d]*xr1;
      sr2 += wr[d]*xr2 - wi[d]*xi2;  si2 += wr[d]*xi2 + wi[d]*xr2;
      sr3 += wr[d]*xr3 - wi[d]*xi3;  si3 += wr[d]*xi3 + wi[d]*xr3;
    }
    int r = px >> 7, c = px & 127;
    lre[r][c]   = sr0;  lim[r][c]   = si0;
    lre[r][c+1] = sr1;  lim[r][c+1] = si1;
    lre[r][c+2] = sr2;  lim[r][c+2] = si2;
    lre[r][c+3] = sr3;  lim[r][c+3] = si3;
  }
  float tws[8], twc[8];
  fft128_mk_tw(tws, twc, 1.0f, lane);
  __syncthreads();
  #pragma unroll
  for (int cc = 0; cc < 8; cc++){
    int c = wv*8 + cc;
    float z0r = lre[lane][c], z0i = lim[lane][c];
    float z1r = lre[lane + 64][c], z1i = lim[lane + 64][c];
    fft128(z0r, z0i, z1r, z1i, tws, twc, lane);
    int k = __brev(lane) >> 25;
    float s, co;
    float a0 = (2.0f*PI_F/16384.0f) * (float)(c * k);
    __sincosf(a0, &s, &co);
    float t = z0r*co - z0i*s; z0i = z0r*s + z0i*co; z0r = t;
    float a1 = (2.0f*PI_F/16384.0f) * (float)(c * (k + 1));
    __sincosf(a1, &s, &co);
    t = z1r*co - z1i*s; z1i = z1r*s + z1i*co; z1r = t;
    lre[k][c] = z0r;     lim[k][c] = z0i;
    lre[k+1][c] = z1r;   lim[k+1][c] = z1i;
  }
  __syncthreads();
  float absv[8][2];
  #pragma unroll
  for (int rr = 0; rr < 8; rr++){
    int r = wv*8 + rr;
    float z0r = lre[r][lane], z0i = lim[r][lane];
    float z1r = lre[r][lane + 64], z1i = lim[r][lane + 64];
    fft128(z0r, z0i, z1r, z1i, tws, twc, lane);
    absv[rr][0] = sqrtf(z0r*z0r + z0i*z0i) * (1.0f/16384.0f);
    absv[rr][1] = sqrtf(z1r*z1r + z1i*z1i) * (1.0f/16384.0f);
  }
  __syncthreads();
  int k2 = __brev(lane) >> 25;
  #pragma unroll
  for (int rr = 0; rr < 8; rr++){
    int r = wv*8 + rr;
    lre[k2][r] = absv[rr][0];
    lre[k2+1][r] = absv[rr][1];
  }
  __syncthreads();
  unsigned short* out = AB + ((long)(b*128 + ch)) * S;
  for (int i = tid; i < S/2; i += 1024){
    int px = i*2; int r = px >> 7, c = px & 127;
    ushort2 v;
    v.x = f2bf(lre[r][c]); v.y = f2bf(lre[r][c+1]);
    *(ushort2*)(out + px) = v;
  }
}

// ---------------- attention stats (bf16 f) ----------------
__global__ __launch_bounds__(256) void gram_part_kernel(
    const unsigned short* __restrict__ Dre, const unsigned short* __restrict__ Dim,
    float* __restrict__ PART){
  int bh = blockIdx.x, slab = blockIdx.y;
  long base = (long)bh * 8 * S;
  int n0 = slab * 2048;
  float accr[36], acci[36], nsq[8];
  #pragma unroll
  for (int i = 0; i < 36; i++){ accr[i] = 0.f; acci[i] = 0.f; }
  #pragma unroll
  for (int i = 0; i < 8; i++) nsq[i] = 0.f;
  for (int it = 0; it < 4; it++){
    int n = n0 + (it*256 + threadIdx.x)*2;
    float xr[8][2], xi[8][2];
    #pragma unroll
    for (int c = 0; c < 8; c++){
      ushort2 ur = *(const ushort2*)(Dre + base + (long)c*S + n);
      ushort2 ui = *(const ushort2*)(Dim + base + (long)c*S + n);
      xr[c][0] = bf2f(ur.x); xr[c][1] = bf2f(ur.y);
      xi[c][0] = bf2f(ui.x); xi[c][1] = bf2f(ui.y);
      nsq[c] += xr[c][0]*xr[c][0] + xi[c][0]*xi[c][0]
              + xr[c][1]*xr[c][1] + xi[c][1]*xi[c][1];
    }
    int t = 0;
    #pragma unroll
    for (int c = 0; c < 8; c++)
      #pragma unroll
      for (int d = c; d < 8; d++){
        accr[t] += xr[c][0]*xr[d][0] - xi[c][0]*xi[d][0]
                 + xr[c][1]*xr[d][1] - xi[c][1]*xi[d][1];
        acci[t] += xr[c][0]*xi[d][0] + xi[c][0]*xr[d][0]
                 + xr[c][1]*xi[d][1] + xi[c][1]*xr[d][1];
        t++;
      }
  }
  __shared__ float red[4][80];
  int wv = threadIdx.x >> 6, lane = threadIdx.x & 63;
  #pragma unroll
  for (int i = 0; i < 80; i++){
    float v = (i < 36) ? accr[i] : (i < 72) ? acci[i - 36] : nsq[i - 72];
    #pragma unroll
    for (int o = 32; o; o >>= 1) v += __shfl_xor(v, o, 64);
    if (lane == 0) red[wv][i] = v;
  }
  __syncthreads();
  if (threadIdx.x < 80){
    int i = threadIdx.x;
    PART[(long)(bh*8 + slab)*80 + i] = red[0][i] + red[1][i] + red[2][i] + red[3][i];
  }
}

__global__ void attn2f_kernel(const float* __restrict__ PART,
    const float* __restrict__ temp, float* __restrict__ ATT2){
  __shared__ float ssum[80];
  __shared__ float sar[64], sai[64];
  int bh = blockIdx.x;
  int t = threadIdx.x;
  if (t < 80){
    float s = 0.f;
    for (int i = 0; i < 8; i++) s += PART[(long)(bh*8 + i)*80 + t];
    ssum[t] = s;
  }
  __syncthreads();
  if (t >= 64) return;
  int lane = t;
  int c = lane >> 3, d = lane & 7;
  int lo = min(c, d), hi = max(c, d);
  int t2 = lo*8 - lo*(lo - 1)/2 + (hi - lo);
  float nnc = fmaxf(sqrtf(ssum[72 + c]), 1e-12f);
  float nnd = fmaxf(sqrtf(ssum[72 + d]), 1e-12f);
  float inv = temp[bh & 7] / (nnc * nnd);
  float ar = ssum[t2] * inv, ai = ssum[36 + t2] * inv;
  float m = ar;
  m = fmaxf(m, __shfl_xor(m, 1, 64)); m = fmaxf(m, __shfl_xor(m, 2, 64)); m = fmaxf(m, __shfl_xor(m, 4, 64));
  float e = __expf(ar - m);
  float su = e;
  su += __shfl_xor(su, 1, 64); su += __shfl_xor(su, 2, 64); su += __shfl_xor(su, 4, 64);
  ar = e / su;
  m = ai;
  m = fmaxf(m, __shfl_xor(m, 1, 64)); m = fmaxf(m, __shfl_xor(m, 2, 64)); m = fmaxf(m, __shfl_xor(m, 4, 64));
  e = __expf(ai - m);
  su = e;
  su += __shfl_xor(su, 1, 64); su += __shfl_xor(su, 2, 64); su += __shfl_xor(su, 4, 64);
  ai = e / su;
  sar[lane] = ar; sai[lane] = ai;
  __syncthreads();
  const float ct[8] = {1.f, 0.70710678f, 0.f, -0.70710678f, -1.f, -0.70710678f, 0.f, 0.70710678f};
  const float st[8] = {0.f, 0.70710678f, 1.f, 0.70710678f, 0.f, -0.70710678f, -1.f, -0.70710678f};
  int cp = c;
  float sr = 0.f, si = 0.f;
  #pragma unroll
  for (int cc = 0; cc < 8; cc++){
    int k = (cc * cp) & 7;
    float a = sar[cc*8 + d], b2 = sai[cc*8 + d];
    sr += ct[k]*a - st[k]*b2;
    si += ct[k]*b2 + st[k]*a;
  }
  float2 v; v.x = sr * 0.125f; v.y = si * 0.125f;
  ((float2*)ATT2)[bh*64 + lane] = v;
}

// gate hidden: H[b][j][px] = relu(bn(wa_j . f.real))  (bf16 f, ushort2 loads)
__global__ __launch_bounds__(256) void gateh_kernel(const unsigned short* __restrict__ Dre,
    const float* __restrict__ wa, const float* __restrict__ sbwa, float* __restrict__ H){
  int b = blockIdx.y;
  int px = (blockIdx.x*256 + threadIdx.x)*2;
  long base = (long)b * 64 * S + px;
  float h0a = 0.f, h1a = 0.f, h2a = 0.f, h3a = 0.f;
  float h0b = 0.f, h1b = 0.f, h2b = 0.f, h3b = 0.f;
  for (int ci = 0; ci < 64; ci++){
    ushort2 u = *(const ushort2*)(Dre + base + (long)ci*S);
    float xa = bf2f(u.x), xb = bf2f(u.y);
    float w0 = wa[ci], w1 = wa[64 + ci], w2 = wa[128 + ci], w3 = wa[192 + ci];
    h0a += w0*xa; h1a += w1*xa; h2a += w2*xa; h3a += w3*xa;
    h0b += w0*xb; h1b += w1*xb; h2b += w2*xb; h3b += w3*xb;
  }
  long ob = (long)b * 4 * S + px;
  float2 v;
  v.x = fmaxf(h0a*sbwa[0] + sbwa[4], 0.f); v.y = fmaxf(h0b*sbwa[0] + sbwa[4], 0.f);
  *(float2*)(H + ob) = v;
  v.x = fmaxf(h1a*sbwa[1] + sbwa[5], 0.f); v.y = fmaxf(h1b*sbwa[1] + sbwa[5], 0.f);
  *(float2*)(H + ob + S) = v;
  v.x = fmaxf(h2a*sbwa[2] + sbwa[6], 0.f); v.y = fmaxf(h2b*sbwa[2] + sbwa[6], 0.f);
  *(float2*)(H + ob + 2*S) = v;
  v.x = fmaxf(h3a*sbwa[3] + sbwa[7], 0.f); v.y = fmaxf(h3b*sbwa[3] + sbwa[7], 0.f);
  *(float2*)(H + ob + 3*S) = v;
}

// ---------------- small kernels ----------------
// mean over relu(sc*(P0+P1)+bb) per (b,ci) plane
__global__ __launch_bounds__(256) void mean2_kernel(const unsigned short* __restrict__ P0,
    const float* __restrict__ sbdc, float* __restrict__ M){
  int p = blockIdx.x;
  int ci = p & 127;
  float sc = sbdc[ci], bb = sbdc[128 + ci];
  long base = (long)p * S;
  float s = 0.f;
  for (int n = threadIdx.x*2; n < S; n += 512){
    ushort2 a0 = *(const ushort2*)(P0 + base + n);
    ushort2 a1 = *(const ushort2*)(P0 + APSTRIDE + base + n);
    s += fmaxf((bf2f(a0.x) + bf2f(a1.x))*sc + bb, 0.f)
       + fmaxf((bf2f(a0.y) + bf2f(a1.y))*sc + bb, 0.f);
  }
  #pragma unroll
  for (int o = 32; o; o >>= 1) s += __shfl_xor(s, o, 64);
  __shared__ float sm[4];
  if ((threadIdx.x & 63) == 0) sm[threadIdx.x >> 6] = s;
  __syncthreads();
  if (threadIdx.x == 0) M[p] = (sm[0] + sm[1] + sm[2] + sm[3]) * (1.0f/16384.0f);
}

// c5 (GAP 1x1 conv + bn_relu) and beff (wf tail contribution) fused: 1 block.
__global__ void c5beff_kernel(const float* __restrict__ W5, const float* __restrict__ sb5,
    const float* __restrict__ WF, const float* __restrict__ sbf,
    const float* __restrict__ M, float* __restrict__ BEFF){
  __shared__ float c5s[256];
  int t = threadIdx.x;
  if (t >= 256) return;
  int b = t >> 6, co = t & 63;
  float s = 0.f;
  for (int ci = 0; ci < 128; ci++) s += W5[co*128 + ci] * M[b*128 + ci];
  c5s[t] = fmaxf(s * sb5[co] + sb5[64 + co], 0.f);
  __syncthreads();
  float s2 = 0.f;
  for (int j = 0; j < 64; j++) s2 += WF[co*320 + 256 + j] * c5s[b*64 + j];
  BEFF[t] = s2 * sbf[co] + sbf[64 + co];
}

// output is FLOAT32 — write float4 (G input is bf16)
__global__ __launch_bounds__(256) void ob_kernel(const unsigned short* __restrict__ Tin,
    const float* __restrict__ wob, const float* __restrict__ bob, float* __restrict__ out){
  int b = blockIdx.y;
  int px = blockIdx.x*1024 + (threadIdx.x & 63)*4 + (threadIdx.x >> 6)*256;
  float b0 = bob[0];
  float4 a; a.x = b0; a.y = b0; a.z = b0; a.w = b0;
  for (int ci = 0; ci < 32; ci++){
    ushort4 v = *(const ushort4*)(Tin + ((long)b*32 + ci)*S + px);
    float w = wob[ci];
    a.x += w*bf2f(v.x); a.y += w*bf2f(v.y); a.z += w*bf2f(v.z); a.w += w*bf2f(v.w);
  }
  *(float4*)(out + (long)b*S + px) = a;
}

// ---------------- launch ----------------
extern "C" void kernel_launch(void* const* d_in, const int* in_sizes, int n_in,
                              void* d_out, int out_size, void* d_ws, size_t ws_size,
                              hipStream_t stream){
  float* ws = (float*)d_ws;
  Ptrs P;
  for (int i = 0; i < 43 && i < n_in; i++) P.p[i] = (const float*)d_in[i];
  float* out = (float*)d_out;

  float* H   = ws + O_H;

  unsigned short* AP0 = (unsigned short*)(ws + O_A);     // bf16 conv_dc partials
  unsigned short* FINB = (unsigned short*)(ws + O_FIN);  // bf16 c1|F2|F3|F4
  unsigned short* CCB  = (unsigned short*)(ws + O_CC);   // bf16 c2/c3/c4, later fused
  unsigned short* GB   = (unsigned short*)(ws + O_G);    // bf16 oa out
  unsigned short* DRE16 = (unsigned short*)(ws + O_DRE);
  unsigned short* DIM16 = (unsigned short*)(ws + O_DIMG);
  unsigned short* AB    = (unsigned short*)(ws + O_A);   // bf16 of|ol, overlays P0 after c1

  unsigned short* XT  = (unsigned short*)(ws + O_DRE);   // conv_dc input (pre-FFT)
  unsigned short* WHd = (unsigned short*)(ws + O_CC);
  unsigned short* WLd = (unsigned short*)(ws + O_CC + 147456);
  unsigned short* WB  = (unsigned short*)(ws + O_WB);
  unsigned short* WP  = (unsigned short*)(ws + O_WP);
  unsigned short* XP  = (unsigned short*)(ws + O_ERE);   // dil/oa input (pre-FFT per branch)

  prep_all_kernel<<<dim3(225), dim3(256), 0, stream>>>(P, ws, WHd, WLd, WB, WP);
  xpad_kernel<<<dim3(130, 4), dim3(256), 0, stream>>>(P.p[0], XT);

  // conv_dc K-split: 2048 blocks, single-bf16 weights, raw bf16 partials P0|P1
  convdc_split_kernel<<<dim3(2048), dim3(256), 0, stream>>>(XT, WHd, AP0);

  mean2_kernel<<<dim3(512), dim3(256), 0, stream>>>(AP0, ws + O_SBDC, ws + O_M);
  c5beff_kernel<<<dim3(1), dim3(256), 0, stream>>>(
      P.p[21], ws + O_SB5, P.p[33], ws + O_SBF, ws + O_M, ws + O_BEFF);

  // c1 -> FIN channels [0,64)  (MFMA, combine partials + dc bn_relu, bf16 out)
  conv1x1_mfma_kernel<0,4,2,1,1><<<dim3(512), dim3(256), 0, stream>>>(
      AP0, 128*S, WP, WP + 8192, ws + O_SB1, ws + O_SBDC, nullptr, 0, FINB, 256*S);

  for (int k = 0; k < 3; k++){
    const float* sb = ws + (k == 0 ? O_SB2 : k == 1 ? O_SB3 : O_SB4);
    const unsigned short* in2 = (k == 0) ? nullptr : FINB + (long)(64*k)*S;
    unsigned short* wh = WB + (k == 0 ? 0 : k == 1 ? 73728 : 147456);
    if (k == 0){
      xpad64_kernel<3,1><<<dim3(134, 4), dim3(256), 0, stream>>>(FINB, in2, 256*S, XP);
      conv3x3_mfma_kernel<3,2,64,1,0><<<dim3(512), dim3(256), 0, stream>>>(
          XP, wh, wh + 36864, sb, CCB);
    } else if (k == 1){
      xpad64_kernel<5,1><<<dim3(138, 4), dim3(256), 0, stream>>>(FINB, in2, 256*S, XP);
      conv3x3_mfma_kernel<5,2,64,1,0><<<dim3(512), dim3(256), 0, stream>>>(
          XP, wh, wh + 36864, sb, CCB);
    } else {
      xpad64_kernel<7,1><<<dim3(142, 4), dim3(256), 0, stream>>>(FINB, in2, 256*S, XP);
      conv3x3_mfma_kernel<7,2,64,1,0><<<dim3(512), dim3(256), 0, stream>>>(
          XP, wh, wh + 36864, sb, CCB);
    }

    // f = fft2(c) -> bf16 (fused per-plane 2D FFT; bf16 in)
    fft2_fwd_kernel<<<dim3(256), dim3(1024), 0, stream>>>(CCB, DRE16, DIM16);
    // attention stats
    gram_part_kernel<<<dim3(32, 8), dim3(256), 0, stream>>>(DRE16, DIM16, ws + O_PART);
    attn2f_kernel<<<dim3(32), dim3(128), 0, stream>>>(ws + O_PART, P.p[25], ws + O_ATT2);
    // gate hidden (4 ch) from f.real
    gateh_kernel<<<dim3(32, 4), dim3(256), 0, stream>>>(DRE16, P.p[27], ws + O_SBWA, H);
    // ol = |ifft2(sigmoid(wb.h+bwb) * f)| -> AB channels [64,128)
    ifft2_gate_abs_ol_kernel<<<dim3(256), dim3(1024), 0, stream>>>(
        DRE16, DIM16, H, P.p[31], P.p[32], AB);
    // of = |ifft_{c,n}(attn @ qkv)| -> AB channels [0,64)  (attn mix fused, XCD-swizzled)
    ifft2_attn_abs_ofT_kernel<<<dim3(256), dim3(1024), 0, stream>>>(
        DRE16, DIM16, ws + O_ATT2, AB);
    // F_k = w_po @ concat(of, ol) + c  (MFMA, bf16 in, bf16 res, bf16 out)
    conv1x1_mfma_kernel<1,4,1,1,1><<<dim3(512), dim3(256), 0, stream>>>(
        AB, 128*S, WP + 16384, WP + 24576, nullptr, nullptr, CCB, 64*S,
        FINB + (long)(64*(k + 1))*S, 256*S);
  }

  // fused = bn_relu(w_f @ concat(c1,F2,F3,F4) + bias_eff(c5)) -> CCB bf16 (single-bf16 weights)
  conv1x1_mfma_kernel<2,8,1,1,0><<<dim3(512), dim3(256), 0, stream>>>(
      FINB, 256*S, WP + 32768, WP + 49152, ws + O_SBF, ws + O_BEFF, nullptr, 0, CCB, 64*S);
  xpad64_kernel<1,1><<<dim3(130, 4), dim3(256), 0, stream>>>(CCB, nullptr, 64*S, XP);
  conv3x3_mfma_kernel<1,2,32,1,1><<<dim3(512), dim3(256), 0, stream>>>(
      XP, WB + 221184, WB + 221184 + 18432, ws + O_SBOA, GB);
  ob_kernel<<<dim3(16, 4), dim3(256), 0, stream>>>(GB, P.p[41], P.p[42], out);
}